// Round 1
// baseline (556.953 us; speedup 1.0000x reference)
//
#include <hip/hip_runtime.h>
#include <hip/hip_bf16.h>

// Problem constants
#define BB 2
#define CC 512
#define NN 2048          // T*H*W = 8*16*16
#define NHEADS 8
#define HDIM 64
#define TOKENS (BB * NN) // 4096

// ---------------------------------------------------------------------------
// Kernel 1: LayerNorm statistics (mean, rstd) per token.
// x layout: [B][C][N] (channel-major, N = T*H*W). Coalesced: thread owns a
// token, loops channels; consecutive threads -> consecutive n.
// ---------------------------------------------------------------------------
__global__ __launch_bounds__(256) void ln_stats_kernel(
    const float* __restrict__ x, float* __restrict__ mu, float* __restrict__ rstd) {
  __shared__ float s_sum[4][64];
  __shared__ float s_sq[4][64];
  int t = threadIdx.x & 63;   // token within block
  int g = threadIdx.x >> 6;   // channel group (0..3)
  int tok = blockIdx.x * 64 + t;
  int b = tok >> 11;          // / NN
  int n = tok & (NN - 1);
  const float* xp = x + (size_t)b * CC * NN + n;
  float s = 0.f, ss = 0.f;
  int c0 = g * 128;
  for (int c = c0; c < c0 + 128; ++c) {
    float v = xp[(size_t)c * NN];
    s += v;
    ss += v * v;
  }
  s_sum[g][t] = s;
  s_sq[g][t] = ss;
  __syncthreads();
  if (g == 0) {
    float S = s_sum[0][t] + s_sum[1][t] + s_sum[2][t] + s_sum[3][t];
    float SS = s_sq[0][t] + s_sq[1][t] + s_sq[2][t] + s_sq[3][t];
    float m = S * (1.0f / CC);
    float var = SS * (1.0f / CC) - m * m;
    mu[tok] = m;
    rstd[tok] = rsqrtf(var + 1e-5f);
  }
}

// ---------------------------------------------------------------------------
// Kernel 2: QKV GEMM with LayerNorm applied on the fly to the B operand.
// qkv[b][o][n] = sum_c w[o][c] * ln(x[b][c][n]) + bias[o]
// M=1536 (o), K=512 (c), N=2048 (n). 64x64 tile, K-step 16, 4x4 per thread.
// ---------------------------------------------------------------------------
__global__ __launch_bounds__(256) void qkv_gemm_kernel(
    const float* __restrict__ x, const float* __restrict__ mu,
    const float* __restrict__ rstd, const float* __restrict__ lnw,
    const float* __restrict__ lnb, const float* __restrict__ w,
    const float* __restrict__ bias, float* __restrict__ qkv) {
  __shared__ float As[16][65];  // [k][m]
  __shared__ float Bs[16][65];  // [k][n]
  int n0 = blockIdx.x * 64;
  int m0 = blockIdx.y * 64;
  int b = blockIdx.z;
  int tid = threadIdx.x;
  int tx = tid & 15, ty = tid >> 4;
  float acc[4][4] = {};
  const float* xb = x + (size_t)b * CC * NN;
  for (int k0 = 0; k0 < CC; k0 += 16) {
#pragma unroll
    for (int l = 0; l < 4; ++l) {
      int e = tid + 256 * l;
      int ol = e >> 4, cl = e & 15;
      As[cl][ol] = w[(size_t)(m0 + ol) * CC + k0 + cl];
    }
#pragma unroll
    for (int l = 0; l < 4; ++l) {
      int e = tid + 256 * l;
      int cl = e >> 6, nl = e & 63;
      int c = k0 + cl, n = n0 + nl;
      float v = xb[(size_t)c * NN + n];
      int tokidx = b * NN + n;
      Bs[cl][nl] = (v - mu[tokidx]) * rstd[tokidx] * lnw[c] + lnb[c];
    }
    __syncthreads();
#pragma unroll
    for (int kk = 0; kk < 16; ++kk) {
      float a[4], bv[4];
#pragma unroll
      for (int i = 0; i < 4; ++i) a[i] = As[kk][ty * 4 + i];
#pragma unroll
      for (int j = 0; j < 4; ++j) bv[j] = Bs[kk][tx * 4 + j];
#pragma unroll
      for (int i = 0; i < 4; ++i)
#pragma unroll
        for (int j = 0; j < 4; ++j) acc[i][j] += a[i] * bv[j];
    }
    __syncthreads();
  }
#pragma unroll
  for (int i = 0; i < 4; ++i) {
    int o = m0 + ty * 4 + i;
    float bi = bias[o];
#pragma unroll
    for (int j = 0; j < 4; ++j) {
      int n = n0 + tx * 4 + j;
      qkv[((size_t)b * 3 * CC + o) * NN + n] = acc[i][j] + bi;
    }
  }
}

// ---------------------------------------------------------------------------
// Kernel 3: flash-style attention. One block = one (b, h, 64-q-row tile).
// q/k/v stored channel-major: [d][n] slices of qkv.
// Online softmax with running max/sum; O accumulated in registers (4x4/thread).
// ---------------------------------------------------------------------------
__global__ __launch_bounds__(256) void attn_kernel(const float* __restrict__ qkv,
                                                   float* __restrict__ xa) {
  __shared__ float Qs[64][65];   // [d][i], pre-scaled
  __shared__ float KVs[64][65];  // [d][m] (K, then reused for V)
  __shared__ float Ss[64][65];   // [i][m] scores -> probabilities
  __shared__ float red[4][64];
  __shared__ float fact[64];
  __shared__ float mrun[64];
  __shared__ float lrun[64];
  int n0 = blockIdx.x * 64;
  int h = blockIdx.y;
  int b = blockIdx.z;
  int tid = threadIdx.x;
  int tx = tid & 15, ty = tid >> 4;
  const float scale = 0.125f;  // 1/sqrt(HDIM)
  const float* qbase = qkv + ((size_t)b * 3 * CC + h * HDIM) * NN;
  const float* kbase = qkv + ((size_t)b * 3 * CC + CC + h * HDIM) * NN;
  const float* vbase = qkv + ((size_t)b * 3 * CC + 2 * CC + h * HDIM) * NN;
#pragma unroll
  for (int l = 0; l < 16; ++l) {
    int e = tid + 256 * l;
    int d = e >> 6, i = e & 63;
    Qs[d][i] = qbase[(size_t)d * NN + n0 + i] * scale;
  }
  if (tid < 64) {
    mrun[tid] = -1e30f;
    lrun[tid] = 0.f;
  }
  float O[4][4] = {};
  __syncthreads();
  for (int mt = 0; mt < NN; mt += 64) {
    // K tile
#pragma unroll
    for (int l = 0; l < 16; ++l) {
      int e = tid + 256 * l;
      int d = e >> 6, m = e & 63;
      KVs[d][m] = kbase[(size_t)d * NN + mt + m];
    }
    __syncthreads();
    // S = Q^T K (pre-scaled)
    float s[4][4] = {};
    for (int d = 0; d < 64; ++d) {
      float a[4], bv[4];
#pragma unroll
      for (int i = 0; i < 4; ++i) a[i] = Qs[d][ty * 4 + i];
#pragma unroll
      for (int j = 0; j < 4; ++j) bv[j] = KVs[d][tx * 4 + j];
#pragma unroll
      for (int i = 0; i < 4; ++i)
#pragma unroll
        for (int j = 0; j < 4; ++j) s[i][j] += a[i] * bv[j];
    }
#pragma unroll
    for (int i = 0; i < 4; ++i)
#pragma unroll
      for (int j = 0; j < 4; ++j) Ss[ty * 4 + i][tx * 4 + j] = s[i][j];
    __syncthreads();
    // partial row max
    {
      int r = tid & 63, q = tid >> 6;
      float pm = -1e30f;
#pragma unroll
      for (int m = q * 16; m < q * 16 + 16; ++m) pm = fmaxf(pm, Ss[r][m]);
      red[q][r] = pm;
    }
    __syncthreads();
    if (tid < 64) {
      int r = tid;
      float tm = fmaxf(fmaxf(red[0][r], red[1][r]), fmaxf(red[2][r], red[3][r]));
      float mold = mrun[r];
      float mnew = fmaxf(mold, tm);
      float f = __expf(mold - mnew);
      mrun[r] = mnew;
      fact[r] = f;
      lrun[r] = lrun[r] * f;
    }
    __syncthreads();
    // exponentiate + partial row sums
    {
      int r = tid & 63, q = tid >> 6;
      float mr = mrun[r];
      float ps = 0.f;
#pragma unroll
      for (int m = q * 16; m < q * 16 + 16; ++m) {
        float p = __expf(Ss[r][m] - mr);
        Ss[r][m] = p;
        ps += p;
      }
      red[q][r] = ps;
    }
    __syncthreads();
    if (tid < 64) {
      int r = tid;
      lrun[r] += red[0][r] + red[1][r] + red[2][r] + red[3][r];
    }
    // V tile (K no longer needed)
#pragma unroll
    for (int l = 0; l < 16; ++l) {
      int e = tid + 256 * l;
      int d = e >> 6, m = e & 63;
      KVs[d][m] = vbase[(size_t)d * NN + mt + m];
    }
    __syncthreads();
    // rescale O, accumulate P*V
    float f[4];
#pragma unroll
    for (int i = 0; i < 4; ++i) f[i] = fact[ty * 4 + i];
#pragma unroll
    for (int i = 0; i < 4; ++i)
#pragma unroll
      for (int j = 0; j < 4; ++j) O[i][j] *= f[i];
    for (int m = 0; m < 64; ++m) {
      float p[4], vv[4];
#pragma unroll
      for (int i = 0; i < 4; ++i) p[i] = Ss[ty * 4 + i][m];
#pragma unroll
      for (int j = 0; j < 4; ++j) vv[j] = KVs[tx * 4 + j][m];
#pragma unroll
      for (int i = 0; i < 4; ++i)
#pragma unroll
        for (int j = 0; j < 4; ++j) O[i][j] += p[i] * vv[j];
    }
    __syncthreads();
  }
  // write xa[b][h*64 + d][n0 + i]
#pragma unroll
  for (int i = 0; i < 4; ++i) {
    float inv = 1.0f / lrun[ty * 4 + i];
#pragma unroll
    for (int j = 0; j < 4; ++j) {
      int d = tx * 4 + j;
      xa[((size_t)b * CC + h * HDIM + d) * NN + n0 + ty * 4 + i] = O[i][j] * inv;
    }
  }
}

// ---------------------------------------------------------------------------
// Kernel 4: proj GEMM + bias + residual (normalized x) epilogue.
// out[b][o][n] = sum_c wproj[o][c]*xa[b][c][n] + bproj[o] + ln(x[b][o][n])
// ---------------------------------------------------------------------------
__global__ __launch_bounds__(256) void proj_gemm_kernel(
    const float* __restrict__ xa, const float* __restrict__ w,
    const float* __restrict__ bias, const float* __restrict__ x,
    const float* __restrict__ mu, const float* __restrict__ rstd,
    const float* __restrict__ lnw, const float* __restrict__ lnb,
    float* __restrict__ out) {
  __shared__ float As[16][65];
  __shared__ float Bs[16][65];
  int n0 = blockIdx.x * 64;
  int m0 = blockIdx.y * 64;
  int b = blockIdx.z;
  int tid = threadIdx.x;
  int tx = tid & 15, ty = tid >> 4;
  float acc[4][4] = {};
  const float* xab = xa + (size_t)b * CC * NN;
  for (int k0 = 0; k0 < CC; k0 += 16) {
#pragma unroll
    for (int l = 0; l < 4; ++l) {
      int e = tid + 256 * l;
      int ol = e >> 4, cl = e & 15;
      As[cl][ol] = w[(size_t)(m0 + ol) * CC + k0 + cl];
    }
#pragma unroll
    for (int l = 0; l < 4; ++l) {
      int e = tid + 256 * l;
      int cl = e >> 6, nl = e & 63;
      Bs[cl][nl] = xab[(size_t)(k0 + cl) * NN + n0 + nl];
    }
    __syncthreads();
#pragma unroll
    for (int kk = 0; kk < 16; ++kk) {
      float a[4], bv[4];
#pragma unroll
      for (int i = 0; i < 4; ++i) a[i] = As[kk][ty * 4 + i];
#pragma unroll
      for (int j = 0; j < 4; ++j) bv[j] = Bs[kk][tx * 4 + j];
#pragma unroll
      for (int i = 0; i < 4; ++i)
#pragma unroll
        for (int j = 0; j < 4; ++j) acc[i][j] += a[i] * bv[j];
    }
    __syncthreads();
  }
#pragma unroll
  for (int i = 0; i < 4; ++i) {
    int o = m0 + ty * 4 + i;
    float bi = bias[o];
    float g = lnw[o], be = lnb[o];
#pragma unroll
    for (int j = 0; j < 4; ++j) {
      int n = n0 + tx * 4 + j;
      int tok = b * NN + n;
      float xv = x[((size_t)b * CC + o) * NN + n];
      float xln = (xv - mu[tok]) * rstd[tok] * g + be;
      out[((size_t)b * CC + o) * NN + n] = acc[i][j] + bi + xln;
    }
  }
}

// ---------------------------------------------------------------------------
extern "C" void kernel_launch(void* const* d_in, const int* in_sizes, int n_in,
                              void* d_out, int out_size, void* d_ws, size_t ws_size,
                              hipStream_t stream) {
  const float* x = (const float*)d_in[0];
  const float* lnw = (const float*)d_in[1];
  const float* lnb = (const float*)d_in[2];
  const float* wqkv = (const float*)d_in[3];
  const float* bqkv = (const float*)d_in[4];
  const float* wproj = (const float*)d_in[5];
  const float* bproj = (const float*)d_in[6];
  float* out = (float*)d_out;

  float* ws = (float*)d_ws;
  float* mu = ws;                       // 4096
  float* rstd = ws + 4096;              // 4096
  float* qkv = ws + 8192;               // 2*1536*2048 = 6291456
  float* xa = qkv + (size_t)BB * 3 * CC * NN;  // 2*512*2048 = 2097152

  hipLaunchKernelGGL(ln_stats_kernel, dim3(64), dim3(256), 0, stream, x, mu, rstd);
  hipLaunchKernelGGL(qkv_gemm_kernel, dim3(32, 24, 2), dim3(256), 0, stream,
                     x, mu, rstd, lnw, lnb, wqkv, bqkv, qkv);
  hipLaunchKernelGGL(attn_kernel, dim3(32, 8, 2), dim3(256), 0, stream, qkv, xa);
  hipLaunchKernelGGL(proj_gemm_kernel, dim3(32, 8, 2), dim3(256), 0, stream,
                     xa, wproj, bproj, x, mu, rstd, lnw, lnb, out);
}

// Round 2
// 282.311 us; speedup vs baseline: 1.9728x; 1.9728x over previous
//
#include <hip/hip_runtime.h>
#include <hip/hip_bf16.h>

// Problem constants
#define BB 2
#define CC 512
#define NN 2048          // T*H*W = 8*16*16
#define NHEADS 8
#define HDIM 64

typedef __attribute__((ext_vector_type(8))) __bf16 bf16x8;
typedef __attribute__((ext_vector_type(4))) __bf16 bf16x4;
typedef __attribute__((ext_vector_type(2))) __bf16 bf16x2;
typedef __attribute__((ext_vector_type(4))) float f32x4;

// ---------------------------------------------------------------------------
// Kernel 1: LayerNorm statistics (mean, rstd) per token.
// ---------------------------------------------------------------------------
__global__ __launch_bounds__(256) void ln_stats_kernel(
    const float* __restrict__ x, float* __restrict__ mu, float* __restrict__ rstd) {
  __shared__ float s_sum[4][64];
  __shared__ float s_sq[4][64];
  int t = threadIdx.x & 63;
  int g = threadIdx.x >> 6;
  int tok = blockIdx.x * 64 + t;
  int b = tok >> 11;
  int n = tok & (NN - 1);
  const float* xp = x + (size_t)b * CC * NN + n;
  float s = 0.f, ss = 0.f;
  int c0 = g * 128;
  for (int c = c0; c < c0 + 128; ++c) {
    float v = xp[(size_t)c * NN];
    s += v;
    ss += v * v;
  }
  s_sum[g][t] = s;
  s_sq[g][t] = ss;
  __syncthreads();
  if (g == 0) {
    float S = s_sum[0][t] + s_sum[1][t] + s_sum[2][t] + s_sum[3][t];
    float SS = s_sq[0][t] + s_sq[1][t] + s_sq[2][t] + s_sq[3][t];
    float m = S * (1.0f / CC);
    float var = SS * (1.0f / CC) - m * m;
    mu[tok] = m;
    rstd[tok] = rsqrtf(var + 1e-5f);
  }
}

// ---------------------------------------------------------------------------
// Kernel 2: QKV GEMM (fp32 compute) with LN fused on B-operand.
// New epilogue: writes bf16 outputs in MFMA-friendly layouts:
//   q_t[b][h][n][d] (pre-scaled by 1/8), k_t[b][h][n][d], v_bf[b][c][n]
// ---------------------------------------------------------------------------
__global__ __launch_bounds__(256) void qkv_gemm_kernel(
    const float* __restrict__ x, const float* __restrict__ mu,
    const float* __restrict__ rstd, const float* __restrict__ lnw,
    const float* __restrict__ lnb, const float* __restrict__ w,
    const float* __restrict__ bias, __bf16* __restrict__ qt,
    __bf16* __restrict__ ktg, __bf16* __restrict__ vbf) {
  __shared__ float As[16][65];  // [k][m]
  __shared__ float Bs[16][65];  // [k][n]
  int n0 = blockIdx.x * 64;
  int m0 = blockIdx.y * 64;
  int b = blockIdx.z;
  int tid = threadIdx.x;
  int tx = tid & 15, ty = tid >> 4;
  float acc[4][4] = {};
  const float* xb = x + (size_t)b * CC * NN;
  for (int k0 = 0; k0 < CC; k0 += 16) {
#pragma unroll
    for (int l = 0; l < 4; ++l) {
      int e = tid + 256 * l;
      int ol = e >> 4, cl = e & 15;
      As[cl][ol] = w[(size_t)(m0 + ol) * CC + k0 + cl];
    }
#pragma unroll
    for (int l = 0; l < 4; ++l) {
      int e = tid + 256 * l;
      int cl = e >> 6, nl = e & 63;
      int c = k0 + cl, n = n0 + nl;
      float v = xb[(size_t)c * NN + n];
      int tokidx = b * NN + n;
      Bs[cl][nl] = (v - mu[tokidx]) * rstd[tokidx] * lnw[c] + lnb[c];
    }
    __syncthreads();
#pragma unroll
    for (int kk = 0; kk < 16; ++kk) {
      float a[4], bv[4];
#pragma unroll
      for (int i = 0; i < 4; ++i) a[i] = As[kk][ty * 4 + i];
#pragma unroll
      for (int j = 0; j < 4; ++j) bv[j] = Bs[kk][tx * 4 + j];
#pragma unroll
      for (int i = 0; i < 4; ++i)
#pragma unroll
        for (int j = 0; j < 4; ++j) acc[i][j] += a[i] * bv[j];
    }
    __syncthreads();
  }
  // Epilogue: all 64 o's in this block are in one section (q/k/v) and one head.
  int sec = m0 >> 9;          // 0=q, 1=k, 2=v
  float bi[4];
#pragma unroll
  for (int i = 0; i < 4; ++i) bi[i] = bias[m0 + ty * 4 + i];
  if (sec < 2) {
    int hh = (m0 >> 6) & 7;
    __bf16* dst = (sec == 0 ? qt : ktg) + (size_t)(b * NHEADS + hh) * NN * HDIM;
    float scl = (sec == 0) ? 0.125f : 1.0f;  // fold 1/sqrt(64) into q
#pragma unroll
    for (int j = 0; j < 4; ++j) {
      int n = n0 + tx * 4 + j;
#pragma unroll
      for (int i = 0; i < 4; i += 2) {
        bf16x2 pk = {(__bf16)((acc[i][j] + bi[i]) * scl),
                     (__bf16)((acc[i + 1][j] + bi[i + 1]) * scl)};
        *(bf16x2*)&dst[(size_t)n * HDIM + ty * 4 + i] = pk;
      }
    }
  } else {
#pragma unroll
    for (int i = 0; i < 4; ++i) {
      int ch = (m0 - 1024) + ty * 4 + i;
      bf16x4 pk = {(__bf16)(acc[i][0] + bi[i]), (__bf16)(acc[i][1] + bi[i]),
                   (__bf16)(acc[i][2] + bi[i]), (__bf16)(acc[i][3] + bi[i])};
      *(bf16x4*)&vbf[((size_t)b * CC + ch) * NN + n0 + tx * 4] = pk;
    }
  }
}

// ---------------------------------------------------------------------------
// Kernel 3: flash attention with bf16 MFMA (16x16x32).
// Block = (b, h, 64-q-row tile); 4 waves, each owns 16 q rows.
// LDS tiles padded to 72 bf16/row (144B stride -> 2-way banks = free).
// mfma D-layout: row = 4*(lane>>4)+reg, col = lane&15.
// A/B frag: m-or-n = lane&15, k = 8*(lane>>4)+j (+32 per second mfma).
// ---------------------------------------------------------------------------
__global__ __launch_bounds__(256) void attn_mfma_kernel(
    const __bf16* __restrict__ qt, const __bf16* __restrict__ ktg,
    const __bf16* __restrict__ vbf, float* __restrict__ xa) {
  __shared__ __align__(16) __bf16 smem[18432];  // 36 KiB
  __bf16(*Qs)[72] = (__bf16(*)[72])(smem);           // [64][72]
  __bf16(*Ks)[72] = (__bf16(*)[72])(smem + 4608);    // [64][72]
  __bf16(*Vs)[72] = (__bf16(*)[72])(smem + 9216);    // [64 d][72 k]
  __bf16(*Ps)[72] = (__bf16(*)[72])(smem + 13824);   // [4*16 q][72 k]
  int tid = threadIdx.x;
  int wid = tid >> 6, lane = tid & 63;
  int g = lane >> 4, c = lane & 15;
  int n0 = blockIdx.x * 64;
  int h = blockIdx.y, b = blockIdx.z;
  int bh = b * NHEADS + h;
  const __bf16* qbase = qt + ((size_t)bh * NN + n0) * HDIM;
  const __bf16* kbase = ktg + (size_t)bh * NN * HDIM;
  const __bf16* vbase = vbf + ((size_t)b * CC + h * HDIM) * NN;

  int sr = tid >> 2, sc = (tid & 3) * 16;  // staging: row, col-start
  {
    const bf16x8* src = (const bf16x8*)(qbase + (size_t)sr * HDIM + sc);
    *(bf16x8*)&Qs[sr][sc] = src[0];
    *(bf16x8*)&Qs[sr][sc + 8] = src[1];
  }
  f32x4 O[4] = {};     // O[dt][r]: d = dt*16+c, q = 4g+r
  float m[4], l[4];
#pragma unroll
  for (int r = 0; r < 4; ++r) { m[r] = -1e30f; l[r] = 0.f; }

  for (int mt = 0; mt < NN; mt += 64) {
    __syncthreads();  // prior tile fully consumed (and Q staged, iter 0)
    {
      const bf16x8* ks = (const bf16x8*)(kbase + (size_t)(mt + sr) * HDIM + sc);
      *(bf16x8*)&Ks[sr][sc] = ks[0];
      *(bf16x8*)&Ks[sr][sc + 8] = ks[1];
      const bf16x8* vs = (const bf16x8*)(vbase + (size_t)sr * NN + mt + sc);
      *(bf16x8*)&Vs[sr][sc] = vs[0];
      *(bf16x8*)&Vs[sr][sc + 8] = vs[1];
    }
    __syncthreads();
    // ---- QK^T: S[16 q][64 k] per wave ----
    int q0 = wid * 16;
    bf16x8 aq0 = *(const bf16x8*)&Qs[q0 + c][g * 8];
    bf16x8 aq1 = *(const bf16x8*)&Qs[q0 + c][32 + g * 8];
    f32x4 s[4];
#pragma unroll
    for (int t4 = 0; t4 < 4; ++t4) {
      bf16x8 bk0 = *(const bf16x8*)&Ks[t4 * 16 + c][g * 8];
      bf16x8 bk1 = *(const bf16x8*)&Ks[t4 * 16 + c][32 + g * 8];
      f32x4 acc = {0.f, 0.f, 0.f, 0.f};
      acc = __builtin_amdgcn_mfma_f32_16x16x32_bf16(aq0, bk0, acc, 0, 0, 0);
      acc = __builtin_amdgcn_mfma_f32_16x16x32_bf16(aq1, bk1, acc, 0, 0, 0);
      s[t4] = acc;
    }
    // ---- online softmax (rows live in 16-lane groups) ----
    float pm[4];
#pragma unroll
    for (int r = 0; r < 4; ++r)
      pm[r] = fmaxf(fmaxf(s[0][r], s[1][r]), fmaxf(s[2][r], s[3][r]));
#pragma unroll
    for (int off = 8; off; off >>= 1)
#pragma unroll
      for (int r = 0; r < 4; ++r) pm[r] = fmaxf(pm[r], __shfl_xor(pm[r], off));
    float fr[4], ps[4];
#pragma unroll
    for (int r = 0; r < 4; ++r) {
      float mn = fmaxf(m[r], pm[r]);
      fr[r] = __expf(m[r] - mn);
      m[r] = mn;
      ps[r] = 0.f;
    }
#pragma unroll
    for (int t4 = 0; t4 < 4; ++t4)
#pragma unroll
      for (int r = 0; r < 4; ++r) {
        float p = __expf(s[t4][r] - m[r]);
        ps[r] += p;
        Ps[wid * 16 + 4 * g + r][t4 * 16 + c] = (__bf16)p;
      }
#pragma unroll
    for (int off = 8; off; off >>= 1)
#pragma unroll
      for (int r = 0; r < 4; ++r) ps[r] += __shfl_xor(ps[r], off);
#pragma unroll
    for (int r = 0; r < 4; ++r) l[r] = l[r] * fr[r] + ps[r];
#pragma unroll
    for (int dt = 0; dt < 4; ++dt)
#pragma unroll
      for (int r = 0; r < 4; ++r) O[dt][r] *= fr[r];
    // ---- PV: O[16 q][64 d] += P * V ----
    bf16x8 ap0 = *(const bf16x8*)&Ps[wid * 16 + c][g * 8];
    bf16x8 ap1 = *(const bf16x8*)&Ps[wid * 16 + c][32 + g * 8];
#pragma unroll
    for (int dt = 0; dt < 4; ++dt) {
      bf16x8 bv0 = *(const bf16x8*)&Vs[dt * 16 + c][g * 8];
      bf16x8 bv1 = *(const bf16x8*)&Vs[dt * 16 + c][32 + g * 8];
      O[dt] = __builtin_amdgcn_mfma_f32_16x16x32_bf16(ap0, bv0, O[dt], 0, 0, 0);
      O[dt] = __builtin_amdgcn_mfma_f32_16x16x32_bf16(ap1, bv1, O[dt], 0, 0, 0);
    }
  }
  // ---- epilogue: normalize, transpose via LDS, coalesced store ----
  __syncthreads();
  float* Os = (float*)smem;  // [64 d][65 n_local], aliases Qs+Ks (dead)
#pragma unroll
  for (int r = 0; r < 4; ++r) {
    float inv = 1.0f / l[r];
#pragma unroll
    for (int dt = 0; dt < 4; ++dt)
      Os[(dt * 16 + c) * 65 + wid * 16 + 4 * g + r] = O[dt][r] * inv;
  }
  __syncthreads();
  {
    float* dst = xa + ((size_t)b * CC + h * HDIM + sr) * NN + n0 + sc;
#pragma unroll
    for (int v4 = 0; v4 < 4; ++v4) {
      float4 val;
      val.x = Os[sr * 65 + sc + v4 * 4 + 0];
      val.y = Os[sr * 65 + sc + v4 * 4 + 1];
      val.z = Os[sr * 65 + sc + v4 * 4 + 2];
      val.w = Os[sr * 65 + sc + v4 * 4 + 3];
      *(float4*)&dst[v4 * 4] = val;
    }
  }
}

// ---------------------------------------------------------------------------
// Kernel 4: proj GEMM (fp32) + bias + residual (normalized x) epilogue.
// ---------------------------------------------------------------------------
__global__ __launch_bounds__(256) void proj_gemm_kernel(
    const float* __restrict__ xa, const float* __restrict__ w,
    const float* __restrict__ bias, const float* __restrict__ x,
    const float* __restrict__ mu, const float* __restrict__ rstd,
    const float* __restrict__ lnw, const float* __restrict__ lnb,
    float* __restrict__ out) {
  __shared__ float As[16][65];
  __shared__ float Bs[16][65];
  int n0 = blockIdx.x * 64;
  int m0 = blockIdx.y * 64;
  int b = blockIdx.z;
  int tid = threadIdx.x;
  int tx = tid & 15, ty = tid >> 4;
  float acc[4][4] = {};
  const float* xab = xa + (size_t)b * CC * NN;
  for (int k0 = 0; k0 < CC; k0 += 16) {
#pragma unroll
    for (int l = 0; l < 4; ++l) {
      int e = tid + 256 * l;
      int ol = e >> 4, cl = e & 15;
      As[cl][ol] = w[(size_t)(m0 + ol) * CC + k0 + cl];
    }
#pragma unroll
    for (int l = 0; l < 4; ++l) {
      int e = tid + 256 * l;
      int cl = e >> 6, nl = e & 63;
      Bs[cl][nl] = xab[(size_t)(k0 + cl) * NN + n0 + nl];
    }
    __syncthreads();
#pragma unroll
    for (int kk = 0; kk < 16; ++kk) {
      float a[4], bv[4];
#pragma unroll
      for (int i = 0; i < 4; ++i) a[i] = As[kk][ty * 4 + i];
#pragma unroll
      for (int j = 0; j < 4; ++j) bv[j] = Bs[kk][tx * 4 + j];
#pragma unroll
      for (int i = 0; i < 4; ++i)
#pragma unroll
        for (int j = 0; j < 4; ++j) acc[i][j] += a[i] * bv[j];
    }
    __syncthreads();
  }
#pragma unroll
  for (int i = 0; i < 4; ++i) {
    int o = m0 + ty * 4 + i;
    float bi = bias[o];
    float g = lnw[o], be = lnb[o];
#pragma unroll
    for (int j = 0; j < 4; ++j) {
      int n = n0 + tx * 4 + j;
      int tok = b * NN + n;
      float xv = x[((size_t)b * CC + o) * NN + n];
      float xln = (xv - mu[tok]) * rstd[tok] * g + be;
      out[((size_t)b * CC + o) * NN + n] = acc[i][j] + bi + xln;
    }
  }
}

// ---------------------------------------------------------------------------
extern "C" void kernel_launch(void* const* d_in, const int* in_sizes, int n_in,
                              void* d_out, int out_size, void* d_ws, size_t ws_size,
                              hipStream_t stream) {
  const float* x = (const float*)d_in[0];
  const float* lnw = (const float*)d_in[1];
  const float* lnb = (const float*)d_in[2];
  const float* wqkv = (const float*)d_in[3];
  const float* bqkv = (const float*)d_in[4];
  const float* wproj = (const float*)d_in[5];
  const float* bproj = (const float*)d_in[6];
  float* out = (float*)d_out;
  (void)in_sizes; (void)n_in; (void)out_size; (void)ws_size;

  char* wsb = (char*)d_ws;
  float* mu = (float*)wsb;                               // 16 KB
  float* rstd = mu + 4096;                               // 16 KB
  const size_t HSZ = (size_t)BB * NHEADS * NN * HDIM;    // 2M elems
  __bf16* qt = (__bf16*)(wsb + 32768);
  __bf16* ktg = qt + HSZ;
  __bf16* vbf = ktg + HSZ;
  float* xa = (float*)(wsb + 32768 + 3 * HSZ * sizeof(__bf16));  // 8 MB

  hipLaunchKernelGGL(ln_stats_kernel, dim3(64), dim3(256), 0, stream, x, mu, rstd);
  hipLaunchKernelGGL(qkv_gemm_kernel, dim3(32, 24, 2), dim3(256), 0, stream,
                     x, mu, rstd, lnw, lnb, wqkv, bqkv, qt, ktg, vbf);
  hipLaunchKernelGGL(attn_mfma_kernel, dim3(32, 8, 2), dim3(256), 0, stream,
                     qt, ktg, vbf, xa);
  hipLaunchKernelGGL(proj_gemm_kernel, dim3(32, 8, 2), dim3(256), 0, stream,
                     xa, wproj, bproj, x, mu, rstd, lnw, lnb, out);
}

// Round 3
// 136.825 us; speedup vs baseline: 4.0705x; 2.0633x over previous
//
#include <hip/hip_runtime.h>
#include <hip/hip_bf16.h>

// Problem constants
#define BB 2
#define CC 512
#define NN 2048          // T*H*W = 8*16*16
#define NHEADS 8
#define HDIM 64

typedef __attribute__((ext_vector_type(8))) __bf16 bf16x8;
typedef __attribute__((ext_vector_type(4))) __bf16 bf16x4;
typedef __attribute__((ext_vector_type(2))) __bf16 bf16x2;
typedef __attribute__((ext_vector_type(4))) float f32x4;

// ---------------------------------------------------------------------------
// Kernel 1: LayerNorm statistics (mean, rstd) per token.
// ---------------------------------------------------------------------------
__global__ __launch_bounds__(256) void ln_stats_kernel(
    const float* __restrict__ x, float* __restrict__ mu, float* __restrict__ rstd) {
  __shared__ float s_sum[4][64];
  __shared__ float s_sq[4][64];
  int t = threadIdx.x & 63;
  int g = threadIdx.x >> 6;
  int tok = blockIdx.x * 64 + t;
  int b = tok >> 11;
  int n = tok & (NN - 1);
  const float* xp = x + (size_t)b * CC * NN + n;
  float s = 0.f, ss = 0.f;
  int c0 = g * 128;
  for (int c = c0; c < c0 + 128; ++c) {
    float v = xp[(size_t)c * NN];
    s += v;
    ss += v * v;
  }
  s_sum[g][t] = s;
  s_sq[g][t] = ss;
  __syncthreads();
  if (g == 0) {
    float S = s_sum[0][t] + s_sum[1][t] + s_sum[2][t] + s_sum[3][t];
    float SS = s_sq[0][t] + s_sq[1][t] + s_sq[2][t] + s_sq[3][t];
    float m = S * (1.0f / CC);
    float var = SS * (1.0f / CC) - m * m;
    mu[tok] = m;
    rstd[tok] = rsqrtf(var + 1e-5f);
  }
}

// ---------------------------------------------------------------------------
// Kernel 1b: LN apply + transpose: x[b][c][n] fp32 -> xln_t[b][n][c] bf16.
// 64x64 tiles through LDS; coalesced read and write.
// ---------------------------------------------------------------------------
__global__ __launch_bounds__(256) void ln_transpose_kernel(
    const float* __restrict__ x, const float* __restrict__ mu,
    const float* __restrict__ rstd, const float* __restrict__ lnw,
    const float* __restrict__ lnb, __bf16* __restrict__ xln_t) {
  __shared__ float Xs[64][68];
  int n0 = blockIdx.x * 64;
  int c0 = blockIdx.y * 64;
  int b = blockIdx.z;
  int tid = threadIdx.x;
#pragma unroll
  for (int l = 0; l < 4; ++l) {
    int e = tid + 256 * l;
    int row = e >> 4, c4 = e & 15;  // row = c local, c4 = n/4 local
    float4 v = *(const float4*)&x[((size_t)b * CC + c0 + row) * NN + n0 + c4 * 4];
    *(float4*)&Xs[row][c4 * 4] = v;
  }
  __syncthreads();
  int sr = tid >> 2;            // n local
  int sc = (tid & 3) * 16;      // c local start
  int tok = b * NN + n0 + sr;
  float mun = mu[tok], rsn = rstd[tok];
  __bf16 outv[16];
#pragma unroll
  for (int j = 0; j < 16; ++j) {
    int c = c0 + sc + j;
    outv[j] = (__bf16)((Xs[sc + j][sr] - mun) * rsn * lnw[c] + lnb[c]);
  }
  __bf16* dst = &xln_t[((size_t)b * NN + n0 + sr) * CC + c0 + sc];
  *(bf16x8*)&dst[0] = *(bf16x8*)&outv[0];
  *(bf16x8*)&dst[8] = *(bf16x8*)&outv[8];
}

// ---------------------------------------------------------------------------
// Kernel 2: QKV GEMM with bf16 MFMA.
// D[o][n] = sum_c W[o][c] * XLN[n][c].  A = W rows (k contiguous after cvt),
// B = xln_t rows (k contiguous). Tile M=64, N=128, K-step 64; 4 waves 2x2.
// SWAP=true (q/k sections): issue mfma(B,A) -> D^T so fragment lanes map to
// contiguous d in q_t/k_t [b][h][n][d]. SWAP=false (v): normal, contiguous n
// in vbf[b][c][n].
// ---------------------------------------------------------------------------
template <bool SWAP>
__global__ __launch_bounds__(256) void qkv_mfma_kernel(
    const __bf16* __restrict__ xln_t, const float* __restrict__ w,
    const float* __restrict__ bias, int m_base, __bf16* __restrict__ qt,
    __bf16* __restrict__ kt, __bf16* __restrict__ vbf) {
  __shared__ __align__(16) __bf16 As[64][72];
  __shared__ __align__(16) __bf16 Bs[128][72];
  int n0 = blockIdx.x * 128;
  int m0 = m_base + blockIdx.y * 64;
  int b = blockIdx.z;
  int tid = threadIdx.x;
  int wid = tid >> 6, lane = tid & 63;
  int g = lane >> 4, c = lane & 15;
  int wr = wid >> 1, wc = wid & 1;
  const __bf16* xln = xln_t + (size_t)b * NN * CC;
  f32x4 acc[2][4] = {};
  for (int k0 = 0; k0 < CC; k0 += 64) {
#pragma unroll
    for (int l = 0; l < 4; ++l) {
      int e = tid + 256 * l;
      int row = e >> 4, c4 = e & 15;
      float4 v = *(const float4*)&w[(size_t)(m0 + row) * CC + k0 + c4 * 4];
      bf16x4 pk = {(__bf16)v.x, (__bf16)v.y, (__bf16)v.z, (__bf16)v.w};
      *(bf16x4*)&As[row][c4 * 4] = pk;
    }
#pragma unroll
    for (int l = 0; l < 4; ++l) {
      int e = tid + 256 * l;
      int row = e >> 3, c8 = e & 7;
      *(bf16x8*)&Bs[row][c8 * 8] =
          *(const bf16x8*)&xln[(size_t)(n0 + row) * CC + k0 + c8 * 8];
    }
    __syncthreads();
    bf16x8 af[2][2], bfr[4][2];
#pragma unroll
    for (int mi = 0; mi < 2; ++mi)
#pragma unroll
      for (int h = 0; h < 2; ++h)
        af[mi][h] = *(const bf16x8*)&As[wr * 32 + mi * 16 + c][h * 32 + g * 8];
#pragma unroll
    for (int nj = 0; nj < 4; ++nj)
#pragma unroll
      for (int h = 0; h < 2; ++h)
        bfr[nj][h] = *(const bf16x8*)&Bs[wc * 64 + nj * 16 + c][h * 32 + g * 8];
#pragma unroll
    for (int mi = 0; mi < 2; ++mi)
#pragma unroll
      for (int nj = 0; nj < 4; ++nj) {
        if (SWAP) {
          acc[mi][nj] = __builtin_amdgcn_mfma_f32_16x16x32_bf16(
              bfr[nj][0], af[mi][0], acc[mi][nj], 0, 0, 0);
          acc[mi][nj] = __builtin_amdgcn_mfma_f32_16x16x32_bf16(
              bfr[nj][1], af[mi][1], acc[mi][nj], 0, 0, 0);
        } else {
          acc[mi][nj] = __builtin_amdgcn_mfma_f32_16x16x32_bf16(
              af[mi][0], bfr[nj][0], acc[mi][nj], 0, 0, 0);
          acc[mi][nj] = __builtin_amdgcn_mfma_f32_16x16x32_bf16(
              af[mi][1], bfr[nj][1], acc[mi][nj], 0, 0, 0);
        }
      }
    __syncthreads();
  }
  if (SWAP) {
    // D^T: row = n (4g+r within nj tile), col = o (c within mi tile)
    int obase = m0 + wr * 32;          // uniform per wave, multiple of 32
    int sec = obase >> 9;              // 0 = q, 1 = k
    int osec = obase & 511;
    int head = osec >> 6;
    int dbase = osec & 63;             // 0 or 32
    __bf16* dst = (sec == 0 ? qt : kt) + (size_t)(b * NHEADS + head) * NN * HDIM;
    float scl = (sec == 0) ? 0.125f : 1.0f;
#pragma unroll
    for (int mi = 0; mi < 2; ++mi) {
      float bo = bias[obase + mi * 16 + c];
      int d = dbase + mi * 16 + c;
#pragma unroll
      for (int nj = 0; nj < 4; ++nj)
#pragma unroll
        for (int r = 0; r < 4; ++r) {
          int n = n0 + wc * 64 + nj * 16 + 4 * g + r;
          dst[(size_t)n * HDIM + d] = (__bf16)((acc[mi][nj][r] + bo) * scl);
        }
    }
  } else {
    // normal: row = o, col = n; write vbf[b][ch][n], ch = o - 1024
#pragma unroll
    for (int mi = 0; mi < 2; ++mi)
#pragma unroll
      for (int r = 0; r < 4; ++r) {
        int o = m0 + wr * 32 + mi * 16 + 4 * g + r;
        int ch = o - 1024;
        float bo = bias[o];
#pragma unroll
        for (int nj = 0; nj < 4; ++nj) {
          int n = n0 + wc * 64 + nj * 16 + c;
          vbf[((size_t)b * CC + ch) * NN + n] = (__bf16)(acc[mi][nj][r] + bo);
        }
      }
  }
}

// ---------------------------------------------------------------------------
// Kernel 3: flash attention with bf16 MFMA (16x16x32).
// Epilogue writes xa_t[b][n][c] bf16 (proj's B-operand layout).
// ---------------------------------------------------------------------------
__global__ __launch_bounds__(256) void attn_mfma_kernel(
    const __bf16* __restrict__ qt, const __bf16* __restrict__ ktg,
    const __bf16* __restrict__ vbf, __bf16* __restrict__ xa_t) {
  __shared__ __align__(16) __bf16 smem[18432];  // 36 KiB
  __bf16(*Qs)[72] = (__bf16(*)[72])(smem);           // [64][72]
  __bf16(*Ks)[72] = (__bf16(*)[72])(smem + 4608);    // [64][72]
  __bf16(*Vs)[72] = (__bf16(*)[72])(smem + 9216);    // [64 d][72 k]
  __bf16(*Ps)[72] = (__bf16(*)[72])(smem + 13824);   // [64 q][72 k]
  int tid = threadIdx.x;
  int wid = tid >> 6, lane = tid & 63;
  int g = lane >> 4, c = lane & 15;
  int n0 = blockIdx.x * 64;
  int h = blockIdx.y, b = blockIdx.z;
  int bh = b * NHEADS + h;
  const __bf16* qbase = qt + ((size_t)bh * NN + n0) * HDIM;
  const __bf16* kbase = ktg + (size_t)bh * NN * HDIM;
  const __bf16* vbase = vbf + ((size_t)b * CC + h * HDIM) * NN;

  int sr = tid >> 2, sc = (tid & 3) * 16;
  {
    const bf16x8* src = (const bf16x8*)(qbase + (size_t)sr * HDIM + sc);
    *(bf16x8*)&Qs[sr][sc] = src[0];
    *(bf16x8*)&Qs[sr][sc + 8] = src[1];
  }
  f32x4 O[4] = {};
  float m[4], l[4];
#pragma unroll
  for (int r = 0; r < 4; ++r) { m[r] = -1e30f; l[r] = 0.f; }

  for (int mt = 0; mt < NN; mt += 64) {
    __syncthreads();
    {
      const bf16x8* ks = (const bf16x8*)(kbase + (size_t)(mt + sr) * HDIM + sc);
      *(bf16x8*)&Ks[sr][sc] = ks[0];
      *(bf16x8*)&Ks[sr][sc + 8] = ks[1];
      const bf16x8* vs = (const bf16x8*)(vbase + (size_t)sr * NN + mt + sc);
      *(bf16x8*)&Vs[sr][sc] = vs[0];
      *(bf16x8*)&Vs[sr][sc + 8] = vs[1];
    }
    __syncthreads();
    int q0 = wid * 16;
    bf16x8 aq0 = *(const bf16x8*)&Qs[q0 + c][g * 8];
    bf16x8 aq1 = *(const bf16x8*)&Qs[q0 + c][32 + g * 8];
    f32x4 s[4];
#pragma unroll
    for (int t4 = 0; t4 < 4; ++t4) {
      bf16x8 bk0 = *(const bf16x8*)&Ks[t4 * 16 + c][g * 8];
      bf16x8 bk1 = *(const bf16x8*)&Ks[t4 * 16 + c][32 + g * 8];
      f32x4 acc = {0.f, 0.f, 0.f, 0.f};
      acc = __builtin_amdgcn_mfma_f32_16x16x32_bf16(aq0, bk0, acc, 0, 0, 0);
      acc = __builtin_amdgcn_mfma_f32_16x16x32_bf16(aq1, bk1, acc, 0, 0, 0);
      s[t4] = acc;
    }
    float pm[4];
#pragma unroll
    for (int r = 0; r < 4; ++r)
      pm[r] = fmaxf(fmaxf(s[0][r], s[1][r]), fmaxf(s[2][r], s[3][r]));
#pragma unroll
    for (int off = 8; off; off >>= 1)
#pragma unroll
      for (int r = 0; r < 4; ++r) pm[r] = fmaxf(pm[r], __shfl_xor(pm[r], off));
    float fr[4], ps[4];
#pragma unroll
    for (int r = 0; r < 4; ++r) {
      float mn = fmaxf(m[r], pm[r]);
      fr[r] = __expf(m[r] - mn);
      m[r] = mn;
      ps[r] = 0.f;
    }
#pragma unroll
    for (int t4 = 0; t4 < 4; ++t4)
#pragma unroll
      for (int r = 0; r < 4; ++r) {
        float p = __expf(s[t4][r] - m[r]);
        ps[r] += p;
        Ps[wid * 16 + 4 * g + r][t4 * 16 + c] = (__bf16)p;
      }
#pragma unroll
    for (int off = 8; off; off >>= 1)
#pragma unroll
      for (int r = 0; r < 4; ++r) ps[r] += __shfl_xor(ps[r], off);
#pragma unroll
    for (int r = 0; r < 4; ++r) l[r] = l[r] * fr[r] + ps[r];
#pragma unroll
    for (int dt = 0; dt < 4; ++dt)
#pragma unroll
      for (int r = 0; r < 4; ++r) O[dt][r] *= fr[r];
    bf16x8 ap0 = *(const bf16x8*)&Ps[wid * 16 + c][g * 8];
    bf16x8 ap1 = *(const bf16x8*)&Ps[wid * 16 + c][32 + g * 8];
#pragma unroll
    for (int dt = 0; dt < 4; ++dt) {
      bf16x8 bv0 = *(const bf16x8*)&Vs[dt * 16 + c][g * 8];
      bf16x8 bv1 = *(const bf16x8*)&Vs[dt * 16 + c][32 + g * 8];
      O[dt] = __builtin_amdgcn_mfma_f32_16x16x32_bf16(ap0, bv0, O[dt], 0, 0, 0);
      O[dt] = __builtin_amdgcn_mfma_f32_16x16x32_bf16(ap1, bv1, O[dt], 0, 0, 0);
    }
  }
  // epilogue: write xa_t[b][n][c] bf16 directly (32B segments per frag row)
#pragma unroll
  for (int r = 0; r < 4; ++r) {
    float inv = 1.0f / l[r];
    size_t row = (size_t)b * NN + n0 + wid * 16 + 4 * g + r;
#pragma unroll
    for (int dt = 0; dt < 4; ++dt)
      xa_t[row * CC + h * HDIM + dt * 16 + c] = (__bf16)(O[dt][r] * inv);
  }
}

// ---------------------------------------------------------------------------
// Kernel 4: proj GEMM bf16 MFMA + bias + residual(normalized x, fp32) epilogue.
// D[o][n] = sum_c Wp[o][c] * XA[n][c]. Tile 64x64, 4 waves 2x2 (32x32 each).
// ---------------------------------------------------------------------------
__global__ __launch_bounds__(256) void proj_mfma_kernel(
    const __bf16* __restrict__ xa_t, const float* __restrict__ w,
    const float* __restrict__ bias, const float* __restrict__ x,
    const float* __restrict__ mu, const float* __restrict__ rstd,
    const float* __restrict__ lnw, const float* __restrict__ lnb,
    float* __restrict__ out) {
  __shared__ __align__(16) __bf16 As[64][72];
  __shared__ __align__(16) __bf16 Bs[64][72];
  int n0 = blockIdx.x * 64;
  int m0 = blockIdx.y * 64;
  int b = blockIdx.z;
  int tid = threadIdx.x;
  int wid = tid >> 6, lane = tid & 63;
  int g = lane >> 4, c = lane & 15;
  int wr = wid >> 1, wc = wid & 1;
  const __bf16* xab = xa_t + (size_t)b * NN * CC;
  f32x4 acc[2][2] = {};
  for (int k0 = 0; k0 < CC; k0 += 64) {
#pragma unroll
    for (int l = 0; l < 4; ++l) {
      int e = tid + 256 * l;
      int row = e >> 4, c4 = e & 15;
      float4 v = *(const float4*)&w[(size_t)(m0 + row) * CC + k0 + c4 * 4];
      bf16x4 pk = {(__bf16)v.x, (__bf16)v.y, (__bf16)v.z, (__bf16)v.w};
      *(bf16x4*)&As[row][c4 * 4] = pk;
    }
#pragma unroll
    for (int l = 0; l < 2; ++l) {
      int e = tid + 256 * l;
      int row = e >> 3, c8 = e & 7;
      *(bf16x8*)&Bs[row][c8 * 8] =
          *(const bf16x8*)&xab[(size_t)(n0 + row) * CC + k0 + c8 * 8];
    }
    __syncthreads();
    bf16x8 af[2][2], bfr[2][2];
#pragma unroll
    for (int mi = 0; mi < 2; ++mi)
#pragma unroll
      for (int h = 0; h < 2; ++h)
        af[mi][h] = *(const bf16x8*)&As[wr * 32 + mi * 16 + c][h * 32 + g * 8];
#pragma unroll
    for (int nj = 0; nj < 2; ++nj)
#pragma unroll
      for (int h = 0; h < 2; ++h)
        bfr[nj][h] = *(const bf16x8*)&Bs[wc * 32 + nj * 16 + c][h * 32 + g * 8];
#pragma unroll
    for (int mi = 0; mi < 2; ++mi)
#pragma unroll
      for (int nj = 0; nj < 2; ++nj) {
        acc[mi][nj] = __builtin_amdgcn_mfma_f32_16x16x32_bf16(
            af[mi][0], bfr[nj][0], acc[mi][nj], 0, 0, 0);
        acc[mi][nj] = __builtin_amdgcn_mfma_f32_16x16x32_bf16(
            af[mi][1], bfr[nj][1], acc[mi][nj], 0, 0, 0);
      }
    __syncthreads();
  }
#pragma unroll
  for (int mi = 0; mi < 2; ++mi)
#pragma unroll
    for (int r = 0; r < 4; ++r) {
      int o = m0 + wr * 32 + mi * 16 + 4 * g + r;
      float bo = bias[o], gw = lnw[o], gb = lnb[o];
#pragma unroll
      for (int nj = 0; nj < 2; ++nj) {
        int n = n0 + wc * 32 + nj * 16 + c;
        int tok = b * NN + n;
        float xv = x[((size_t)b * CC + o) * NN + n];
        float xlnv = (xv - mu[tok]) * rstd[tok] * gw + gb;
        out[((size_t)b * CC + o) * NN + n] = acc[mi][nj][r] + bo + xlnv;
      }
    }
}

// ---------------------------------------------------------------------------
extern "C" void kernel_launch(void* const* d_in, const int* in_sizes, int n_in,
                              void* d_out, int out_size, void* d_ws, size_t ws_size,
                              hipStream_t stream) {
  const float* x = (const float*)d_in[0];
  const float* lnw = (const float*)d_in[1];
  const float* lnb = (const float*)d_in[2];
  const float* wqkv = (const float*)d_in[3];
  const float* bqkv = (const float*)d_in[4];
  const float* wproj = (const float*)d_in[5];
  const float* bproj = (const float*)d_in[6];
  float* out = (float*)d_out;
  (void)in_sizes; (void)n_in; (void)out_size; (void)ws_size;

  char* wsb = (char*)d_ws;
  float* mu = (float*)wsb;                               // 16 KB
  float* rstd = mu + 4096;                               // 16 KB
  const size_t HSZ = (size_t)BB * NHEADS * NN * HDIM;    // 2M elems
  __bf16* qt = (__bf16*)(wsb + 32768);                   // 4 MB
  __bf16* kt = qt + HSZ;                                 // 4 MB
  __bf16* vbf = kt + HSZ;                                // 4 MB
  __bf16* xln_t = vbf + HSZ;                             // 4 MB
  __bf16* xa_t = xln_t + HSZ;                            // 4 MB

  hipLaunchKernelGGL(ln_stats_kernel, dim3(64), dim3(256), 0, stream, x, mu, rstd);
  hipLaunchKernelGGL(ln_transpose_kernel, dim3(32, 8, 2), dim3(256), 0, stream,
                     x, mu, rstd, lnw, lnb, xln_t);
  hipLaunchKernelGGL(qkv_mfma_kernel<true>, dim3(16, 16, 2), dim3(256), 0, stream,
                     xln_t, wqkv, bqkv, 0, qt, kt, vbf);
  hipLaunchKernelGGL(qkv_mfma_kernel<false>, dim3(16, 8, 2), dim3(256), 0, stream,
                     xln_t, wqkv, bqkv, 1024, qt, kt, vbf);
  hipLaunchKernelGGL(attn_mfma_kernel, dim3(32, 8, 2), dim3(256), 0, stream,
                     qt, kt, vbf, xa_t);
  hipLaunchKernelGGL(proj_mfma_kernel, dim3(32, 8, 2), dim3(256), 0, stream,
                     xa_t, wproj, bproj, x, mu, rstd, lnw, lnb, out);
}

// Round 4
// 125.524 us; speedup vs baseline: 4.4370x; 1.0900x over previous
//
#include <hip/hip_runtime.h>
#include <hip/hip_bf16.h>

// Problem constants
#define BB 2
#define CC 512
#define NN 2048          // T*H*W = 8*16*16
#define NHEADS 8
#define HDIM 64

typedef __attribute__((ext_vector_type(8))) __bf16 bf16x8;
typedef __attribute__((ext_vector_type(4))) __bf16 bf16x4;
typedef __attribute__((ext_vector_type(2))) __bf16 bf16x2;
typedef __attribute__((ext_vector_type(4))) float f32x4;

#define QSCALE 0.18033688f  // 0.125 * log2(e): QK^T lands in exp2 domain

// ---------------------------------------------------------------------------
// Kernel 1: LayerNorm statistics (mean, rstd) per token.
// ---------------------------------------------------------------------------
__global__ __launch_bounds__(256) void ln_stats_kernel(
    const float* __restrict__ x, float* __restrict__ mu, float* __restrict__ rstd) {
  __shared__ float s_sum[4][64];
  __shared__ float s_sq[4][64];
  int t = threadIdx.x & 63;
  int g = threadIdx.x >> 6;
  int tok = blockIdx.x * 64 + t;
  int b = tok >> 11;
  int n = tok & (NN - 1);
  const float* xp = x + (size_t)b * CC * NN + n;
  float s = 0.f, ss = 0.f;
  int c0 = g * 128;
  for (int c = c0; c < c0 + 128; ++c) {
    float v = xp[(size_t)c * NN];
    s += v;
    ss += v * v;
  }
  s_sum[g][t] = s;
  s_sq[g][t] = ss;
  __syncthreads();
  if (g == 0) {
    float S = s_sum[0][t] + s_sum[1][t] + s_sum[2][t] + s_sum[3][t];
    float SS = s_sq[0][t] + s_sq[1][t] + s_sq[2][t] + s_sq[3][t];
    float m = S * (1.0f / CC);
    float var = SS * (1.0f / CC) - m * m;
    mu[tok] = m;
    rstd[tok] = rsqrtf(var + 1e-5f);
  }
}

// ---------------------------------------------------------------------------
// Kernel 1b: LN apply + transpose: x[b][c][n] fp32 -> xln_t[b][n][c] bf16.
// ---------------------------------------------------------------------------
__global__ __launch_bounds__(256) void ln_transpose_kernel(
    const float* __restrict__ x, const float* __restrict__ mu,
    const float* __restrict__ rstd, const float* __restrict__ lnw,
    const float* __restrict__ lnb, __bf16* __restrict__ xln_t) {
  __shared__ float Xs[64][68];
  int n0 = blockIdx.x * 64;
  int c0 = blockIdx.y * 64;
  int b = blockIdx.z;
  int tid = threadIdx.x;
#pragma unroll
  for (int l = 0; l < 4; ++l) {
    int e = tid + 256 * l;
    int row = e >> 4, c4 = e & 15;
    float4 v = *(const float4*)&x[((size_t)b * CC + c0 + row) * NN + n0 + c4 * 4];
    *(float4*)&Xs[row][c4 * 4] = v;
  }
  __syncthreads();
  int sr = tid >> 2;
  int sc = (tid & 3) * 16;
  int tok = b * NN + n0 + sr;
  float mun = mu[tok], rsn = rstd[tok];
  __bf16 outv[16];
#pragma unroll
  for (int j = 0; j < 16; ++j) {
    int c = c0 + sc + j;
    outv[j] = (__bf16)((Xs[sc + j][sr] - mun) * rsn * lnw[c] + lnb[c]);
  }
  __bf16* dst = &xln_t[((size_t)b * NN + n0 + sr) * CC + c0 + sc];
  *(bf16x8*)&dst[0] = *(bf16x8*)&outv[0];
  *(bf16x8*)&dst[8] = *(bf16x8*)&outv[8];
}

// ---------------------------------------------------------------------------
// Kernel 2: QKV GEMM with bf16 MFMA. (q pre-scaled by 0.125*log2e for exp2
// softmax downstream.)
// ---------------------------------------------------------------------------
template <bool SWAP>
__global__ __launch_bounds__(256) void qkv_mfma_kernel(
    const __bf16* __restrict__ xln_t, const float* __restrict__ w,
    const float* __restrict__ bias, int m_base, __bf16* __restrict__ qt,
    __bf16* __restrict__ kt, __bf16* __restrict__ vbf) {
  __shared__ __align__(16) __bf16 As[64][72];
  __shared__ __align__(16) __bf16 Bs[128][72];
  int n0 = blockIdx.x * 128;
  int m0 = m_base + blockIdx.y * 64;
  int b = blockIdx.z;
  int tid = threadIdx.x;
  int wid = tid >> 6, lane = tid & 63;
  int g = lane >> 4, c = lane & 15;
  int wr = wid >> 1, wc = wid & 1;
  const __bf16* xln = xln_t + (size_t)b * NN * CC;
  f32x4 acc[2][4] = {};
  for (int k0 = 0; k0 < CC; k0 += 64) {
#pragma unroll
    for (int l = 0; l < 4; ++l) {
      int e = tid + 256 * l;
      int row = e >> 4, c4 = e & 15;
      float4 v = *(const float4*)&w[(size_t)(m0 + row) * CC + k0 + c4 * 4];
      bf16x4 pk = {(__bf16)v.x, (__bf16)v.y, (__bf16)v.z, (__bf16)v.w};
      *(bf16x4*)&As[row][c4 * 4] = pk;
    }
#pragma unroll
    for (int l = 0; l < 4; ++l) {
      int e = tid + 256 * l;
      int row = e >> 3, c8 = e & 7;
      *(bf16x8*)&Bs[row][c8 * 8] =
          *(const bf16x8*)&xln[(size_t)(n0 + row) * CC + k0 + c8 * 8];
    }
    __syncthreads();
    bf16x8 af[2][2], bfr[4][2];
#pragma unroll
    for (int mi = 0; mi < 2; ++mi)
#pragma unroll
      for (int h = 0; h < 2; ++h)
        af[mi][h] = *(const bf16x8*)&As[wr * 32 + mi * 16 + c][h * 32 + g * 8];
#pragma unroll
    for (int nj = 0; nj < 4; ++nj)
#pragma unroll
      for (int h = 0; h < 2; ++h)
        bfr[nj][h] = *(const bf16x8*)&Bs[wc * 64 + nj * 16 + c][h * 32 + g * 8];
#pragma unroll
    for (int mi = 0; mi < 2; ++mi)
#pragma unroll
      for (int nj = 0; nj < 4; ++nj) {
        if (SWAP) {
          acc[mi][nj] = __builtin_amdgcn_mfma_f32_16x16x32_bf16(
              bfr[nj][0], af[mi][0], acc[mi][nj], 0, 0, 0);
          acc[mi][nj] = __builtin_amdgcn_mfma_f32_16x16x32_bf16(
              bfr[nj][1], af[mi][1], acc[mi][nj], 0, 0, 0);
        } else {
          acc[mi][nj] = __builtin_amdgcn_mfma_f32_16x16x32_bf16(
              af[mi][0], bfr[nj][0], acc[mi][nj], 0, 0, 0);
          acc[mi][nj] = __builtin_amdgcn_mfma_f32_16x16x32_bf16(
              af[mi][1], bfr[nj][1], acc[mi][nj], 0, 0, 0);
        }
      }
    __syncthreads();
  }
  if (SWAP) {
    int obase = m0 + wr * 32;
    int sec = obase >> 9;
    int osec = obase & 511;
    int head = osec >> 6;
    int dbase = osec & 63;
    __bf16* dst = (sec == 0 ? qt : kt) + (size_t)(b * NHEADS + head) * NN * HDIM;
    float scl = (sec == 0) ? QSCALE : 1.0f;
#pragma unroll
    for (int mi = 0; mi < 2; ++mi) {
      float bo = bias[obase + mi * 16 + c];
      int d = dbase + mi * 16 + c;
#pragma unroll
      for (int nj = 0; nj < 4; ++nj)
#pragma unroll
        for (int r = 0; r < 4; ++r) {
          int n = n0 + wc * 64 + nj * 16 + 4 * g + r;
          dst[(size_t)n * HDIM + d] = (__bf16)((acc[mi][nj][r] + bo) * scl);
        }
    }
  } else {
#pragma unroll
    for (int mi = 0; mi < 2; ++mi)
#pragma unroll
      for (int r = 0; r < 4; ++r) {
        int o = m0 + wr * 32 + mi * 16 + 4 * g + r;
        int ch = o - 1024;
        float bo = bias[o];
#pragma unroll
        for (int nj = 0; nj < 4; ++nj) {
          int n = n0 + wc * 64 + nj * 16 + c;
          vbf[((size_t)b * CC + ch) * NN + n] = (__bf16)(acc[mi][nj][r] + bo);
        }
      }
  }
}

// ---------------------------------------------------------------------------
// Kernel 3: flash attention, bf16 MFMA, double-buffered K/V, ONE barrier per
// KV tile. Q in registers; exp2-domain softmax; per-wave P bounce (no sync).
// ---------------------------------------------------------------------------
__global__ __launch_bounds__(256, 3) void attn_mfma_kernel(
    const __bf16* __restrict__ qt, const __bf16* __restrict__ ktg,
    const __bf16* __restrict__ vbf, __bf16* __restrict__ xa_t) {
  __shared__ __align__(16) __bf16 Kb[2][64][72];  // 18 KiB
  __shared__ __align__(16) __bf16 Vb[2][64][72];  // 18 KiB
  __shared__ __align__(16) __bf16 Ps[64][72];     // 9 KiB
  int tid = threadIdx.x;
  int wid = tid >> 6, lane = tid & 63;
  int g = lane >> 4, c = lane & 15;
  int n0 = blockIdx.x * 64;
  int h = blockIdx.y, b = blockIdx.z;
  int bh = b * NHEADS + h;
  const __bf16* qbase = qt + ((size_t)bh * NN + n0) * HDIM;
  const __bf16* kbase = ktg + (size_t)bh * NN * HDIM;
  const __bf16* vbase = vbf + ((size_t)b * CC + h * HDIM) * NN;

  int sr = tid >> 2, sc = (tid & 3) * 16;
  // prologue: load tile 0 into regs
  bf16x8 kr0 = *(const bf16x8*)(kbase + (size_t)sr * HDIM + sc);
  bf16x8 kr1 = *(const bf16x8*)(kbase + (size_t)sr * HDIM + sc + 8);
  bf16x8 vr0 = *(const bf16x8*)(vbase + (size_t)sr * NN + sc);
  bf16x8 vr1 = *(const bf16x8*)(vbase + (size_t)sr * NN + sc + 8);
  // Q fragments (held in regs for the whole kernel)
  bf16x8 aq0 = *(const bf16x8*)(qbase + (size_t)(wid * 16 + c) * HDIM + g * 8);
  bf16x8 aq1 = *(const bf16x8*)(qbase + (size_t)(wid * 16 + c) * HDIM + 32 + g * 8);
  *(bf16x8*)&Kb[0][sr][sc] = kr0;
  *(bf16x8*)&Kb[0][sr][sc + 8] = kr1;
  *(bf16x8*)&Vb[0][sr][sc] = vr0;
  *(bf16x8*)&Vb[0][sr][sc + 8] = vr1;

  f32x4 O[4] = {};
  float m[4], l[4];
#pragma unroll
  for (int r = 0; r < 4; ++r) { m[r] = -1e30f; l[r] = 0.f; }
  __syncthreads();

  for (int t = 0; t < NN / 64; ++t) {
    int cur = t & 1;
    bool pf = (t + 1 < NN / 64);
    int mt = (t + 1) * 64;
    if (pf) {  // issue next-tile loads early; latency hides under compute
      kr0 = *(const bf16x8*)(kbase + (size_t)(mt + sr) * HDIM + sc);
      kr1 = *(const bf16x8*)(kbase + (size_t)(mt + sr) * HDIM + sc + 8);
      vr0 = *(const bf16x8*)(vbase + (size_t)sr * NN + mt + sc);
      vr1 = *(const bf16x8*)(vbase + (size_t)sr * NN + mt + sc + 8);
    }
    // ---- QK^T ----
    f32x4 s[4];
#pragma unroll
    for (int t4 = 0; t4 < 4; ++t4) {
      bf16x8 bk0 = *(const bf16x8*)&Kb[cur][t4 * 16 + c][g * 8];
      bf16x8 bk1 = *(const bf16x8*)&Kb[cur][t4 * 16 + c][32 + g * 8];
      f32x4 acc = {0.f, 0.f, 0.f, 0.f};
      acc = __builtin_amdgcn_mfma_f32_16x16x32_bf16(aq0, bk0, acc, 0, 0, 0);
      acc = __builtin_amdgcn_mfma_f32_16x16x32_bf16(aq1, bk1, acc, 0, 0, 0);
      s[t4] = acc;
    }
    // ---- online softmax (exp2 domain; rows live in 16-lane groups) ----
    float pm[4];
#pragma unroll
    for (int r = 0; r < 4; ++r)
      pm[r] = fmaxf(fmaxf(s[0][r], s[1][r]), fmaxf(s[2][r], s[3][r]));
#pragma unroll
    for (int off = 8; off; off >>= 1)
#pragma unroll
      for (int r = 0; r < 4; ++r) pm[r] = fmaxf(pm[r], __shfl_xor(pm[r], off));
    float fr[4], ps[4];
#pragma unroll
    for (int r = 0; r < 4; ++r) {
      float mn = fmaxf(m[r], pm[r]);
      fr[r] = exp2f(m[r] - mn);
      m[r] = mn;
      ps[r] = 0.f;
    }
#pragma unroll
    for (int t4 = 0; t4 < 4; ++t4)
#pragma unroll
      for (int r = 0; r < 4; ++r) {
        float p = exp2f(s[t4][r] - m[r]);
        ps[r] += p;
        Ps[wid * 16 + 4 * g + r][t4 * 16 + c] = (__bf16)p;
      }
#pragma unroll
    for (int off = 8; off; off >>= 1)
#pragma unroll
      for (int r = 0; r < 4; ++r) ps[r] += __shfl_xor(ps[r], off);
#pragma unroll
    for (int r = 0; r < 4; ++r) l[r] = l[r] * fr[r] + ps[r];
#pragma unroll
    for (int dt = 0; dt < 4; ++dt)
#pragma unroll
      for (int r = 0; r < 4; ++r) O[dt][r] *= fr[r];
    // ---- PV ----
    bf16x8 ap0 = *(const bf16x8*)&Ps[wid * 16 + c][g * 8];
    bf16x8 ap1 = *(const bf16x8*)&Ps[wid * 16 + c][32 + g * 8];
#pragma unroll
    for (int dt = 0; dt < 4; ++dt) {
      bf16x8 bv0 = *(const bf16x8*)&Vb[cur][dt * 16 + c][g * 8];
      bf16x8 bv1 = *(const bf16x8*)&Vb[cur][dt * 16 + c][32 + g * 8];
      O[dt] = __builtin_amdgcn_mfma_f32_16x16x32_bf16(ap0, bv0, O[dt], 0, 0, 0);
      O[dt] = __builtin_amdgcn_mfma_f32_16x16x32_bf16(ap1, bv1, O[dt], 0, 0, 0);
    }
    // ---- write prefetched tile into the other buffer ----
    if (pf) {
      *(bf16x8*)&Kb[cur ^ 1][sr][sc] = kr0;
      *(bf16x8*)&Kb[cur ^ 1][sr][sc + 8] = kr1;
      *(bf16x8*)&Vb[cur ^ 1][sr][sc] = vr0;
      *(bf16x8*)&Vb[cur ^ 1][sr][sc + 8] = vr1;
    }
    __syncthreads();
  }
  // epilogue: write xa_t[b][n][c] bf16
#pragma unroll
  for (int r = 0; r < 4; ++r) {
    float inv = 1.0f / l[r];
    size_t row = (size_t)b * NN + n0 + wid * 16 + 4 * g + r;
#pragma unroll
    for (int dt = 0; dt < 4; ++dt)
      xa_t[row * CC + h * HDIM + dt * 16 + c] = (__bf16)(O[dt][r] * inv);
  }
}

// ---------------------------------------------------------------------------
// Kernel 4: proj GEMM bf16 MFMA + bias + residual(normalized x, fp32) epilogue.
// ---------------------------------------------------------------------------
__global__ __launch_bounds__(256) void proj_mfma_kernel(
    const __bf16* __restrict__ xa_t, const float* __restrict__ w,
    const float* __restrict__ bias, const float* __restrict__ x,
    const float* __restrict__ mu, const float* __restrict__ rstd,
    const float* __restrict__ lnw, const float* __restrict__ lnb,
    float* __restrict__ out) {
  __shared__ __align__(16) __bf16 As[64][72];
  __shared__ __align__(16) __bf16 Bs[64][72];
  int n0 = blockIdx.x * 64;
  int m0 = blockIdx.y * 64;
  int b = blockIdx.z;
  int tid = threadIdx.x;
  int wid = tid >> 6, lane = tid & 63;
  int g = lane >> 4, c = lane & 15;
  int wr = wid >> 1, wc = wid & 1;
  const __bf16* xab = xa_t + (size_t)b * NN * CC;
  f32x4 acc[2][2] = {};
  for (int k0 = 0; k0 < CC; k0 += 64) {
#pragma unroll
    for (int l = 0; l < 4; ++l) {
      int e = tid + 256 * l;
      int row = e >> 4, c4 = e & 15;
      float4 v = *(const float4*)&w[(size_t)(m0 + row) * CC + k0 + c4 * 4];
      bf16x4 pk = {(__bf16)v.x, (__bf16)v.y, (__bf16)v.z, (__bf16)v.w};
      *(bf16x4*)&As[row][c4 * 4] = pk;
    }
#pragma unroll
    for (int l = 0; l < 2; ++l) {
      int e = tid + 256 * l;
      int row = e >> 3, c8 = e & 7;
      *(bf16x8*)&Bs[row][c8 * 8] =
          *(const bf16x8*)&xab[(size_t)(n0 + row) * CC + k0 + c8 * 8];
    }
    __syncthreads();
    bf16x8 af[2][2], bfr[2][2];
#pragma unroll
    for (int mi = 0; mi < 2; ++mi)
#pragma unroll
      for (int h = 0; h < 2; ++h)
        af[mi][h] = *(const bf16x8*)&As[wr * 32 + mi * 16 + c][h * 32 + g * 8];
#pragma unroll
    for (int nj = 0; nj < 2; ++nj)
#pragma unroll
      for (int h = 0; h < 2; ++h)
        bfr[nj][h] = *(const bf16x8*)&Bs[wc * 32 + nj * 16 + c][h * 32 + g * 8];
#pragma unroll
    for (int mi = 0; mi < 2; ++mi)
#pragma unroll
      for (int nj = 0; nj < 2; ++nj) {
        acc[mi][nj] = __builtin_amdgcn_mfma_f32_16x16x32_bf16(
            af[mi][0], bfr[nj][0], acc[mi][nj], 0, 0, 0);
        acc[mi][nj] = __builtin_amdgcn_mfma_f32_16x16x32_bf16(
            af[mi][1], bfr[nj][1], acc[mi][nj], 0, 0, 0);
      }
    __syncthreads();
  }
#pragma unroll
  for (int mi = 0; mi < 2; ++mi)
#pragma unroll
    for (int r = 0; r < 4; ++r) {
      int o = m0 + wr * 32 + mi * 16 + 4 * g + r;
      float bo = bias[o], gw = lnw[o], gb = lnb[o];
#pragma unroll
      for (int nj = 0; nj < 2; ++nj) {
        int n = n0 + wc * 32 + nj * 16 + c;
        int tok = b * NN + n;
        float xv = x[((size_t)b * CC + o) * NN + n];
        float xlnv = (xv - mu[tok]) * rstd[tok] * gw + gb;
        out[((size_t)b * CC + o) * NN + n] = acc[mi][nj][r] + bo + xlnv;
      }
    }
}

// ---------------------------------------------------------------------------
extern "C" void kernel_launch(void* const* d_in, const int* in_sizes, int n_in,
                              void* d_out, int out_size, void* d_ws, size_t ws_size,
                              hipStream_t stream) {
  const float* x = (const float*)d_in[0];
  const float* lnw = (const float*)d_in[1];
  const float* lnb = (const float*)d_in[2];
  const float* wqkv = (const float*)d_in[3];
  const float* bqkv = (const float*)d_in[4];
  const float* wproj = (const float*)d_in[5];
  const float* bproj = (const float*)d_in[6];
  float* out = (float*)d_out;
  (void)in_sizes; (void)n_in; (void)out_size; (void)ws_size;

  char* wsb = (char*)d_ws;
  float* mu = (float*)wsb;                               // 16 KB
  float* rstd = mu + 4096;                               // 16 KB
  const size_t HSZ = (size_t)BB * NHEADS * NN * HDIM;    // 2M elems
  __bf16* qt = (__bf16*)(wsb + 32768);                   // 4 MB
  __bf16* kt = qt + HSZ;                                 // 4 MB
  __bf16* vbf = kt + HSZ;                                // 4 MB
  __bf16* xln_t = vbf + HSZ;                             // 4 MB
  __bf16* xa_t = xln_t + HSZ;                            // 4 MB

  hipLaunchKernelGGL(ln_stats_kernel, dim3(64), dim3(256), 0, stream, x, mu, rstd);
  hipLaunchKernelGGL(ln_transpose_kernel, dim3(32, 8, 2), dim3(256), 0, stream,
                     x, mu, rstd, lnw, lnb, xln_t);
  hipLaunchKernelGGL(qkv_mfma_kernel<true>, dim3(16, 16, 2), dim3(256), 0, stream,
                     xln_t, wqkv, bqkv, 0, qt, kt, vbf);
  hipLaunchKernelGGL(qkv_mfma_kernel<false>, dim3(16, 8, 2), dim3(256), 0, stream,
                     xln_t, wqkv, bqkv, 1024, qt, kt, vbf);
  hipLaunchKernelGGL(attn_mfma_kernel, dim3(32, 8, 2), dim3(256), 0, stream,
                     qt, kt, vbf, xa_t);
  hipLaunchKernelGGL(proj_mfma_kernel, dim3(32, 8, 2), dim3(256), 0, stream,
                     xa_t, wproj, bproj, x, mu, rstd, lnw, lnb, out);
}

// Round 5
// 105.860 us; speedup vs baseline: 5.2612x; 1.1858x over previous
//
#include <hip/hip_runtime.h>
#include <hip/hip_bf16.h>

// Problem constants
#define BB 2
#define CC 512
#define NN 2048          // T*H*W = 8*16*16
#define NHEADS 8
#define HDIM 64

typedef __attribute__((ext_vector_type(8))) __bf16 bf16x8;
typedef __attribute__((ext_vector_type(4))) __bf16 bf16x4;
typedef __attribute__((ext_vector_type(2))) __bf16 bf16x2;
typedef __attribute__((ext_vector_type(4))) float f32x4;

#define QSCALE 0.18033688f  // 0.125 * log2(e): QK^T lands in exp2 domain

// ---------------------------------------------------------------------------
// Kernel 1: LayerNorm statistics (mean, rstd) per token.
// ---------------------------------------------------------------------------
__global__ __launch_bounds__(256) void ln_stats_kernel(
    const float* __restrict__ x, float* __restrict__ mu, float* __restrict__ rstd) {
  __shared__ float s_sum[4][64];
  __shared__ float s_sq[4][64];
  int t = threadIdx.x & 63;
  int g = threadIdx.x >> 6;
  int tok = blockIdx.x * 64 + t;
  int b = tok >> 11;
  int n = tok & (NN - 1);
  const float* xp = x + (size_t)b * CC * NN + n;
  float s = 0.f, ss = 0.f;
  int c0 = g * 128;
  for (int c = c0; c < c0 + 128; ++c) {
    float v = xp[(size_t)c * NN];
    s += v;
    ss += v * v;
  }
  s_sum[g][t] = s;
  s_sq[g][t] = ss;
  __syncthreads();
  if (g == 0) {
    float S = s_sum[0][t] + s_sum[1][t] + s_sum[2][t] + s_sum[3][t];
    float SS = s_sq[0][t] + s_sq[1][t] + s_sq[2][t] + s_sq[3][t];
    float m = S * (1.0f / CC);
    float var = SS * (1.0f / CC) - m * m;
    mu[tok] = m;
    rstd[tok] = rsqrtf(var + 1e-5f);
  }
}

// ---------------------------------------------------------------------------
// Kernel 1b: LN apply + transpose: x[b][c][n] fp32 -> xln_t[b][n][c] bf16.
// ---------------------------------------------------------------------------
__global__ __launch_bounds__(256) void ln_transpose_kernel(
    const float* __restrict__ x, const float* __restrict__ mu,
    const float* __restrict__ rstd, const float* __restrict__ lnw,
    const float* __restrict__ lnb, __bf16* __restrict__ xln_t) {
  __shared__ float Xs[64][68];
  int n0 = blockIdx.x * 64;
  int c0 = blockIdx.y * 64;
  int b = blockIdx.z;
  int tid = threadIdx.x;
#pragma unroll
  for (int l = 0; l < 4; ++l) {
    int e = tid + 256 * l;
    int row = e >> 4, c4 = e & 15;
    float4 v = *(const float4*)&x[((size_t)b * CC + c0 + row) * NN + n0 + c4 * 4];
    *(float4*)&Xs[row][c4 * 4] = v;
  }
  __syncthreads();
  int sr = tid >> 2;
  int sc = (tid & 3) * 16;
  int tok = b * NN + n0 + sr;
  float mun = mu[tok], rsn = rstd[tok];
  __bf16 outv[16];
#pragma unroll
  for (int j = 0; j < 16; ++j) {
    int c = c0 + sc + j;
    outv[j] = (__bf16)((Xs[sc + j][sr] - mun) * rsn * lnw[c] + lnb[c]);
  }
  __bf16* dst = &xln_t[((size_t)b * NN + n0 + sr) * CC + c0 + sc];
  *(bf16x8*)&dst[0] = *(bf16x8*)&outv[0];
  *(bf16x8*)&dst[8] = *(bf16x8*)&outv[8];
}

// ---------------------------------------------------------------------------
// Kernel 2: QKV GEMM with bf16 MFMA. (q pre-scaled by 0.125*log2e for exp2
// softmax downstream.)
// ---------------------------------------------------------------------------
template <bool SWAP>
__global__ __launch_bounds__(256) void qkv_mfma_kernel(
    const __bf16* __restrict__ xln_t, const float* __restrict__ w,
    const float* __restrict__ bias, int m_base, __bf16* __restrict__ qt,
    __bf16* __restrict__ kt, __bf16* __restrict__ vbf) {
  __shared__ __align__(16) __bf16 As[64][72];
  __shared__ __align__(16) __bf16 Bs[128][72];
  int n0 = blockIdx.x * 128;
  int m0 = m_base + blockIdx.y * 64;
  int b = blockIdx.z;
  int tid = threadIdx.x;
  int wid = tid >> 6, lane = tid & 63;
  int g = lane >> 4, c = lane & 15;
  int wr = wid >> 1, wc = wid & 1;
  const __bf16* xln = xln_t + (size_t)b * NN * CC;
  f32x4 acc[2][4] = {};
  for (int k0 = 0; k0 < CC; k0 += 64) {
#pragma unroll
    for (int l = 0; l < 4; ++l) {
      int e = tid + 256 * l;
      int row = e >> 4, c4 = e & 15;
      float4 v = *(const float4*)&w[(size_t)(m0 + row) * CC + k0 + c4 * 4];
      bf16x4 pk = {(__bf16)v.x, (__bf16)v.y, (__bf16)v.z, (__bf16)v.w};
      *(bf16x4*)&As[row][c4 * 4] = pk;
    }
#pragma unroll
    for (int l = 0; l < 4; ++l) {
      int e = tid + 256 * l;
      int row = e >> 3, c8 = e & 7;
      *(bf16x8*)&Bs[row][c8 * 8] =
          *(const bf16x8*)&xln[(size_t)(n0 + row) * CC + k0 + c8 * 8];
    }
    __syncthreads();
    bf16x8 af[2][2], bfr[4][2];
#pragma unroll
    for (int mi = 0; mi < 2; ++mi)
#pragma unroll
      for (int h = 0; h < 2; ++h)
        af[mi][h] = *(const bf16x8*)&As[wr * 32 + mi * 16 + c][h * 32 + g * 8];
#pragma unroll
    for (int nj = 0; nj < 4; ++nj)
#pragma unroll
      for (int h = 0; h < 2; ++h)
        bfr[nj][h] = *(const bf16x8*)&Bs[wc * 64 + nj * 16 + c][h * 32 + g * 8];
#pragma unroll
    for (int mi = 0; mi < 2; ++mi)
#pragma unroll
      for (int nj = 0; nj < 4; ++nj) {
        if (SWAP) {
          acc[mi][nj] = __builtin_amdgcn_mfma_f32_16x16x32_bf16(
              bfr[nj][0], af[mi][0], acc[mi][nj], 0, 0, 0);
          acc[mi][nj] = __builtin_amdgcn_mfma_f32_16x16x32_bf16(
              bfr[nj][1], af[mi][1], acc[mi][nj], 0, 0, 0);
        } else {
          acc[mi][nj] = __builtin_amdgcn_mfma_f32_16x16x32_bf16(
              af[mi][0], bfr[nj][0], acc[mi][nj], 0, 0, 0);
          acc[mi][nj] = __builtin_amdgcn_mfma_f32_16x16x32_bf16(
              af[mi][1], bfr[nj][1], acc[mi][nj], 0, 0, 0);
        }
      }
    __syncthreads();
  }
  if (SWAP) {
    int obase = m0 + wr * 32;
    int sec = obase >> 9;
    int osec = obase & 511;
    int head = osec >> 6;
    int dbase = osec & 63;
    __bf16* dst = (sec == 0 ? qt : kt) + (size_t)(b * NHEADS + head) * NN * HDIM;
    float scl = (sec == 0) ? QSCALE : 1.0f;
#pragma unroll
    for (int mi = 0; mi < 2; ++mi) {
      float bo = bias[obase + mi * 16 + c];
      int d = dbase + mi * 16 + c;
#pragma unroll
      for (int nj = 0; nj < 4; ++nj)
#pragma unroll
        for (int r = 0; r < 4; ++r) {
          int n = n0 + wc * 64 + nj * 16 + 4 * g + r;
          dst[(size_t)n * HDIM + d] = (__bf16)((acc[mi][nj][r] + bo) * scl);
        }
    }
  } else {
#pragma unroll
    for (int mi = 0; mi < 2; ++mi)
#pragma unroll
      for (int r = 0; r < 4; ++r) {
        int o = m0 + wr * 32 + mi * 16 + 4 * g + r;
        int ch = o - 1024;
        float bo = bias[o];
#pragma unroll
        for (int nj = 0; nj < 4; ++nj) {
          int n = n0 + wc * 64 + nj * 16 + c;
          vbf[((size_t)b * CC + ch) * NN + n] = (__bf16)(acc[mi][nj][r] + bo);
        }
      }
  }
}

// ---------------------------------------------------------------------------
// Kernel 3: flash attention, bf16 MFMA, double-buffered K/V, ONE barrier per
// KV tile. Swapped QK^T (S^T layout): each lane owns one q-row -> in-lane
// softmax reduction (2 shuffle rounds), scalar m/l, packed b64 P-writes.
// ---------------------------------------------------------------------------
__global__ __launch_bounds__(256, 2) void attn_mfma_kernel(
    const __bf16* __restrict__ qt, const __bf16* __restrict__ ktg,
    const __bf16* __restrict__ vbf, __bf16* __restrict__ xa_t) {
  __shared__ __align__(16) __bf16 Kb[2][64][72];  // 18 KiB
  __shared__ __align__(16) __bf16 Vb[2][64][72];  // 18 KiB
  __shared__ __align__(16) __bf16 Ps[64][72];     // 9 KiB
  int tid = threadIdx.x;
  int wid = tid >> 6, lane = tid & 63;
  int g = lane >> 4, c = lane & 15;
  int n0 = blockIdx.x * 64;
  int h = blockIdx.y, b = blockIdx.z;
  int bh = b * NHEADS + h;
  const __bf16* qbase = qt + ((size_t)bh * NN + n0) * HDIM;
  const __bf16* kbase = ktg + (size_t)bh * NN * HDIM;
  const __bf16* vbase = vbf + ((size_t)b * CC + h * HDIM) * NN;

  int sr = tid >> 2, sc = (tid & 3) * 16;
  // prologue: load tile 0 into regs
  bf16x8 kr0 = *(const bf16x8*)(kbase + (size_t)sr * HDIM + sc);
  bf16x8 kr1 = *(const bf16x8*)(kbase + (size_t)sr * HDIM + sc + 8);
  bf16x8 vr0 = *(const bf16x8*)(vbase + (size_t)sr * NN + sc);
  bf16x8 vr1 = *(const bf16x8*)(vbase + (size_t)sr * NN + sc + 8);
  // Q fragments (held in regs for the whole kernel)
  bf16x8 aq0 = *(const bf16x8*)(qbase + (size_t)(wid * 16 + c) * HDIM + g * 8);
  bf16x8 aq1 = *(const bf16x8*)(qbase + (size_t)(wid * 16 + c) * HDIM + 32 + g * 8);
  *(bf16x8*)&Kb[0][sr][sc] = kr0;
  *(bf16x8*)&Kb[0][sr][sc + 8] = kr1;
  *(bf16x8*)&Vb[0][sr][sc] = vr0;
  *(bf16x8*)&Vb[0][sr][sc + 8] = vr1;

  f32x4 O[4] = {};        // O[dt][r]: q-row = 4g+r, d = dt*16+c
  float m_ = -1e30f;      // running max of q-row c (replicated over 4 g-lanes)
  float l_ = 0.f;         // running sum of q-row c
  __syncthreads();

  for (int t = 0; t < NN / 64; ++t) {
    int cur = t & 1;
    bool pf = (t + 1 < NN / 64);
    int mt = (t + 1) * 64;
    if (pf) {  // issue next-tile loads early; latency hides under compute
      kr0 = *(const bf16x8*)(kbase + (size_t)(mt + sr) * HDIM + sc);
      kr1 = *(const bf16x8*)(kbase + (size_t)(mt + sr) * HDIM + sc + 8);
      vr0 = *(const bf16x8*)(vbase + (size_t)sr * NN + mt + sc);
      vr1 = *(const bf16x8*)(vbase + (size_t)sr * NN + mt + sc + 8);
    }
    // ---- QK^T swapped: st[t4] = K_frag * Q_frag = S^T ----
    // lane (c,g), reg r, tile t4 -> S[q-row = c][k = 16*t4 + 4*g + r]
    f32x4 st[4];
    __builtin_amdgcn_s_setprio(1);
#pragma unroll
    for (int t4 = 0; t4 < 4; ++t4) {
      bf16x8 bk0 = *(const bf16x8*)&Kb[cur][t4 * 16 + c][g * 8];
      bf16x8 bk1 = *(const bf16x8*)&Kb[cur][t4 * 16 + c][32 + g * 8];
      f32x4 acc = {0.f, 0.f, 0.f, 0.f};
      acc = __builtin_amdgcn_mfma_f32_16x16x32_bf16(bk0, aq0, acc, 0, 0, 0);
      acc = __builtin_amdgcn_mfma_f32_16x16x32_bf16(bk1, aq1, acc, 0, 0, 0);
      st[t4] = acc;
    }
    __builtin_amdgcn_s_setprio(0);
    // ---- online softmax: row c is lane-local (16 values) ----
    float pm = st[0][0];
#pragma unroll
    for (int t4 = 0; t4 < 4; ++t4)
#pragma unroll
      for (int r = 0; r < 4; ++r) pm = fmaxf(pm, st[t4][r]);
    pm = fmaxf(pm, __shfl_xor(pm, 16));
    pm = fmaxf(pm, __shfl_xor(pm, 32));
    float mn = fmaxf(m_, pm);
    float fscale = exp2f(m_ - mn);
    m_ = mn;
    float ps = 0.f;
#pragma unroll
    for (int t4 = 0; t4 < 4; ++t4) {
      float p0 = exp2f(st[t4][0] - m_);
      float p1 = exp2f(st[t4][1] - m_);
      float p2 = exp2f(st[t4][2] - m_);
      float p3 = exp2f(st[t4][3] - m_);
      ps += (p0 + p1) + (p2 + p3);
      bf16x4 quad = {(__bf16)p0, (__bf16)p1, (__bf16)p2, (__bf16)p3};
      *(bf16x4*)&Ps[wid * 16 + c][t4 * 16 + 4 * g] = quad;
    }
    ps += __shfl_xor(ps, 16);
    ps += __shfl_xor(ps, 32);
    l_ = l_ * fscale + ps;
    // ---- O rescale: factor for row 4g+r lives at lane (4g+r) ----
    float frow[4];
#pragma unroll
    for (int r = 0; r < 4; ++r) frow[r] = __shfl(fscale, 4 * g + r);
#pragma unroll
    for (int dt = 0; dt < 4; ++dt)
#pragma unroll
      for (int r = 0; r < 4; ++r) O[dt][r] *= frow[r];
    // ---- PV ----
    bf16x8 ap0 = *(const bf16x8*)&Ps[wid * 16 + c][g * 8];
    bf16x8 ap1 = *(const bf16x8*)&Ps[wid * 16 + c][32 + g * 8];
    __builtin_amdgcn_s_setprio(1);
#pragma unroll
    for (int dt = 0; dt < 4; ++dt) {
      bf16x8 bv0 = *(const bf16x8*)&Vb[cur][dt * 16 + c][g * 8];
      bf16x8 bv1 = *(const bf16x8*)&Vb[cur][dt * 16 + c][32 + g * 8];
      O[dt] = __builtin_amdgcn_mfma_f32_16x16x32_bf16(ap0, bv0, O[dt], 0, 0, 0);
      O[dt] = __builtin_amdgcn_mfma_f32_16x16x32_bf16(ap1, bv1, O[dt], 0, 0, 0);
    }
    __builtin_amdgcn_s_setprio(0);
    // ---- write prefetched tile into the other buffer ----
    if (pf) {
      *(bf16x8*)&Kb[cur ^ 1][sr][sc] = kr0;
      *(bf16x8*)&Kb[cur ^ 1][sr][sc + 8] = kr1;
      *(bf16x8*)&Vb[cur ^ 1][sr][sc] = vr0;
      *(bf16x8*)&Vb[cur ^ 1][sr][sc + 8] = vr1;
    }
    __syncthreads();
  }
  // epilogue: l for row 4g+r lives at lane (4g+r); write xa_t[b][n][c] bf16
  float lrow[4];
#pragma unroll
  for (int r = 0; r < 4; ++r) lrow[r] = __shfl(l_, 4 * g + r);
#pragma unroll
  for (int r = 0; r < 4; ++r) {
    float inv = 1.0f / lrow[r];
    size_t row = (size_t)b * NN + n0 + wid * 16 + 4 * g + r;
#pragma unroll
    for (int dt = 0; dt < 4; ++dt)
      xa_t[row * CC + h * HDIM + dt * 16 + c] = (__bf16)(O[dt][r] * inv);
  }
}

// ---------------------------------------------------------------------------
// Kernel 4: proj GEMM bf16 MFMA + bias + residual(normalized x, fp32) epilogue.
// ---------------------------------------------------------------------------
__global__ __launch_bounds__(256) void proj_mfma_kernel(
    const __bf16* __restrict__ xa_t, const float* __restrict__ w,
    const float* __restrict__ bias, const float* __restrict__ x,
    const float* __restrict__ mu, const float* __restrict__ rstd,
    const float* __restrict__ lnw, const float* __restrict__ lnb,
    float* __restrict__ out) {
  __shared__ __align__(16) __bf16 As[64][72];
  __shared__ __align__(16) __bf16 Bs[64][72];
  int n0 = blockIdx.x * 64;
  int m0 = blockIdx.y * 64;
  int b = blockIdx.z;
  int tid = threadIdx.x;
  int wid = tid >> 6, lane = tid & 63;
  int g = lane >> 4, c = lane & 15;
  int wr = wid >> 1, wc = wid & 1;
  const __bf16* xab = xa_t + (size_t)b * NN * CC;
  f32x4 acc[2][2] = {};
  for (int k0 = 0; k0 < CC; k0 += 64) {
#pragma unroll
    for (int l = 0; l < 4; ++l) {
      int e = tid + 256 * l;
      int row = e >> 4, c4 = e & 15;
      float4 v = *(const float4*)&w[(size_t)(m0 + row) * CC + k0 + c4 * 4];
      bf16x4 pk = {(__bf16)v.x, (__bf16)v.y, (__bf16)v.z, (__bf16)v.w};
      *(bf16x4*)&As[row][c4 * 4] = pk;
    }
#pragma unroll
    for (int l = 0; l < 2; ++l) {
      int e = tid + 256 * l;
      int row = e >> 3, c8 = e & 7;
      *(bf16x8*)&Bs[row][c8 * 8] =
          *(const bf16x8*)&xab[(size_t)(n0 + row) * CC + k0 + c8 * 8];
    }
    __syncthreads();
    bf16x8 af[2][2], bfr[2][2];
#pragma unroll
    for (int mi = 0; mi < 2; ++mi)
#pragma unroll
      for (int h = 0; h < 2; ++h)
        af[mi][h] = *(const bf16x8*)&As[wr * 32 + mi * 16 + c][h * 32 + g * 8];
#pragma unroll
    for (int nj = 0; nj < 2; ++nj)
#pragma unroll
      for (int h = 0; h < 2; ++h)
        bfr[nj][h] = *(const bf16x8*)&Bs[wc * 32 + nj * 16 + c][h * 32 + g * 8];
#pragma unroll
    for (int mi = 0; mi < 2; ++mi)
#pragma unroll
      for (int nj = 0; nj < 2; ++nj) {
        acc[mi][nj] = __builtin_amdgcn_mfma_f32_16x16x32_bf16(
            af[mi][0], bfr[nj][0], acc[mi][nj], 0, 0, 0);
        acc[mi][nj] = __builtin_amdgcn_mfma_f32_16x16x32_bf16(
            af[mi][1], bfr[nj][1], acc[mi][nj], 0, 0, 0);
      }
    __syncthreads();
  }
#pragma unroll
  for (int mi = 0; mi < 2; ++mi)
#pragma unroll
    for (int r = 0; r < 4; ++r) {
      int o = m0 + wr * 32 + mi * 16 + 4 * g + r;
      float bo = bias[o], gw = lnw[o], gb = lnb[o];
#pragma unroll
      for (int nj = 0; nj < 2; ++nj) {
        int n = n0 + wc * 32 + nj * 16 + c;
        int tok = b * NN + n;
        float xv = x[((size_t)b * CC + o) * NN + n];
        float xlnv = (xv - mu[tok]) * rstd[tok] * gw + gb;
        out[((size_t)b * CC + o) * NN + n] = acc[mi][nj][r] + bo + xlnv;
      }
    }
}

// ---------------------------------------------------------------------------
extern "C" void kernel_launch(void* const* d_in, const int* in_sizes, int n_in,
                              void* d_out, int out_size, void* d_ws, size_t ws_size,
                              hipStream_t stream) {
  const float* x = (const float*)d_in[0];
  const float* lnw = (const float*)d_in[1];
  const float* lnb = (const float*)d_in[2];
  const float* wqkv = (const float*)d_in[3];
  const float* bqkv = (const float*)d_in[4];
  const float* wproj = (const float*)d_in[5];
  const float* bproj = (const float*)d_in[6];
  float* out = (float*)d_out;
  (void)in_sizes; (void)n_in; (void)out_size; (void)ws_size;

  char* wsb = (char*)d_ws;
  float* mu = (float*)wsb;                               // 16 KB
  float* rstd = mu + 4096;                               // 16 KB
  const size_t HSZ = (size_t)BB * NHEADS * NN * HDIM;    // 2M elems
  __bf16* qt = (__bf16*)(wsb + 32768);                   // 4 MB
  __bf16* kt = qt + HSZ;                                 // 4 MB
  __bf16* vbf = kt + HSZ;                                // 4 MB
  __bf16* xln_t = vbf + HSZ;                             // 4 MB
  __bf16* xa_t = xln_t + HSZ;                            // 4 MB

  hipLaunchKernelGGL(ln_stats_kernel, dim3(64), dim3(256), 0, stream, x, mu, rstd);
  hipLaunchKernelGGL(ln_transpose_kernel, dim3(32, 8, 2), dim3(256), 0, stream,
                     x, mu, rstd, lnw, lnb, xln_t);
  hipLaunchKernelGGL(qkv_mfma_kernel<true>, dim3(16, 16, 2), dim3(256), 0, stream,
                     xln_t, wqkv, bqkv, 0, qt, kt, vbf);
  hipLaunchKernelGGL(qkv_mfma_kernel<false>, dim3(16, 8, 2), dim3(256), 0, stream,
                     xln_t, wqkv, bqkv, 1024, qt, kt, vbf);
  hipLaunchKernelGGL(attn_mfma_kernel, dim3(32, 8, 2), dim3(256), 0, stream,
                     qt, kt, vbf, xa_t);
  hipLaunchKernelGGL(proj_mfma_kernel, dim3(32, 8, 2), dim3(256), 0, stream,
                     xa_t, wproj, bproj, x, mu, rstd, lnw, lnb, out);
}

// Round 6
// 79.524 us; speedup vs baseline: 7.0036x; 1.3312x over previous
//
#include <hip/hip_runtime.h>
#include <hip/hip_bf16.h>

// Problem constants
#define BB 2
#define CC 512
#define NN 2048          // T*H*W = 8*16*16
#define NHEADS 8
#define HDIM 64

typedef __attribute__((ext_vector_type(8))) __bf16 bf16x8;
typedef __attribute__((ext_vector_type(4))) __bf16 bf16x4;
typedef __attribute__((ext_vector_type(2))) __bf16 bf16x2;
typedef __attribute__((ext_vector_type(4))) float f32x4;

#define QSCALE 0.18033688f  // 0.125 * log2(e): QK^T lands in exp2 domain

// ---------------------------------------------------------------------------
// Kernel 1: LayerNorm statistics. 256 blocks x 16 tokens (was 64 blocks).
// ---------------------------------------------------------------------------
__global__ __launch_bounds__(256) void ln_stats_kernel(
    const float* __restrict__ x, float* __restrict__ mu, float* __restrict__ rstd) {
  __shared__ float rs[16][16];
  __shared__ float rq[16][16];
  int tl = threadIdx.x & 15;   // token within block
  int cg = threadIdx.x >> 4;   // channel group (32 ch each)
  int tok = blockIdx.x * 16 + tl;
  int b = tok >> 11;
  int n = tok & (NN - 1);
  const float* xp = x + (size_t)b * CC * NN + n;
  float s = 0.f, ss = 0.f;
  int c0 = cg * 32;
#pragma unroll 8
  for (int c = c0; c < c0 + 32; ++c) {
    float v = xp[(size_t)c * NN];
    s += v;
    ss += v * v;
  }
  rs[cg][tl] = s;
  rq[cg][tl] = ss;
  __syncthreads();
  if (threadIdx.x < 16) {
    int t = threadIdx.x;
    float S = 0.f, SS = 0.f;
#pragma unroll
    for (int gidx = 0; gidx < 16; ++gidx) {
      S += rs[gidx][t];
      SS += rq[gidx][t];
    }
    float m = S * (1.0f / CC);
    float var = SS * (1.0f / CC) - m * m;
    int tk = blockIdx.x * 16 + t;
    mu[tk] = m;
    rstd[tk] = rsqrtf(var + 1e-5f);
  }
}

// ---------------------------------------------------------------------------
// Kernel 1b: LN apply + transpose: x[b][c][n] fp32 -> xln_t[b][n][c] bf16.
// ---------------------------------------------------------------------------
__global__ __launch_bounds__(256) void ln_transpose_kernel(
    const float* __restrict__ x, const float* __restrict__ mu,
    const float* __restrict__ rstd, const float* __restrict__ lnw,
    const float* __restrict__ lnb, __bf16* __restrict__ xln_t) {
  __shared__ float Xs[64][68];
  int n0 = blockIdx.x * 64;
  int c0 = blockIdx.y * 64;
  int b = blockIdx.z;
  int tid = threadIdx.x;
#pragma unroll
  for (int l = 0; l < 4; ++l) {
    int e = tid + 256 * l;
    int row = e >> 4, c4 = e & 15;
    float4 v = *(const float4*)&x[((size_t)b * CC + c0 + row) * NN + n0 + c4 * 4];
    *(float4*)&Xs[row][c4 * 4] = v;
  }
  __syncthreads();
  int sr = tid >> 2;
  int sc = (tid & 3) * 16;
  int tok = b * NN + n0 + sr;
  float mun = mu[tok], rsn = rstd[tok];
  __bf16 outv[16];
#pragma unroll
  for (int j = 0; j < 16; ++j) {
    int c = c0 + sc + j;
    outv[j] = (__bf16)((Xs[sc + j][sr] - mun) * rsn * lnw[c] + lnb[c]);
  }
  __bf16* dst = &xln_t[((size_t)b * NN + n0 + sr) * CC + c0 + sc];
  *(bf16x8*)&dst[0] = *(bf16x8*)&outv[0];
  *(bf16x8*)&dst[8] = *(bf16x8*)&outv[8];
}

// ---------------------------------------------------------------------------
// Kernel 2: merged QKV GEMM, bf16 MFMA, reg-staged double-buffered LDS,
// ONE barrier per K-step. blockIdx.y<16 -> q/k (swapped mfma, [n][d] out);
// else -> v ([c][n] out).
// ---------------------------------------------------------------------------
__global__ __launch_bounds__(256) void qkv_mfma_kernel(
    const __bf16* __restrict__ xln_t, const float* __restrict__ w,
    const float* __restrict__ bias, __bf16* __restrict__ qt,
    __bf16* __restrict__ kt, __bf16* __restrict__ vbf) {
  __shared__ __align__(16) __bf16 As[2][64][68];   // 17.0 KiB
  __shared__ __align__(16) __bf16 Bs[2][128][68];  // 34.0 KiB
  int n0 = blockIdx.x * 128;
  bool swap = blockIdx.y < 16;
  int m0 = swap ? blockIdx.y * 64 : 1024 + ((int)blockIdx.y - 16) * 64;
  int b = blockIdx.z;
  int tid = threadIdx.x;
  int wid = tid >> 6, lane = tid & 63;
  int g = lane >> 4, c = lane & 15;
  int wr = wid >> 1, wc = wid & 1;
  const __bf16* xln = xln_t + (size_t)b * NN * CC;
  int arow = tid >> 4, ac4 = tid & 15;
  int brow = tid >> 3, bc8 = tid & 7;

  float4 wA[4];
  bf16x8 xB[4];
  auto LOADREGS = [&](int k0) {
#pragma unroll
    for (int l = 0; l < 4; ++l)
      wA[l] = *(const float4*)&w[(size_t)(m0 + arow + 16 * l) * CC + k0 + ac4 * 4];
#pragma unroll
    for (int l = 0; l < 4; ++l)
      xB[l] = *(const bf16x8*)&xln[(size_t)(n0 + brow + 32 * l) * CC + k0 + bc8 * 8];
  };
  auto STORELDS = [&](int buf) {
#pragma unroll
    for (int l = 0; l < 4; ++l) {
      bf16x4 pk = {(__bf16)wA[l].x, (__bf16)wA[l].y, (__bf16)wA[l].z,
                   (__bf16)wA[l].w};
      *(bf16x4*)&As[buf][arow + 16 * l][ac4 * 4] = pk;
    }
#pragma unroll
    for (int l = 0; l < 4; ++l)
      *(bf16x8*)&Bs[buf][brow + 32 * l][bc8 * 8] = xB[l];
  };

  LOADREGS(0);
  STORELDS(0);
  __syncthreads();
  f32x4 acc[2][4] = {};
  for (int ktile = 0; ktile < 8; ++ktile) {
    int cur = ktile & 1;
    if (ktile < 7) LOADREGS((ktile + 1) * 64);
#pragma unroll
    for (int hh = 0; hh < 2; ++hh) {
      bf16x8 af[2], bfr[4];
#pragma unroll
      for (int mi = 0; mi < 2; ++mi)
        af[mi] = *(const bf16x8*)&As[cur][wr * 32 + mi * 16 + c][hh * 32 + g * 8];
#pragma unroll
      for (int nj = 0; nj < 4; ++nj)
        bfr[nj] = *(const bf16x8*)&Bs[cur][wc * 64 + nj * 16 + c][hh * 32 + g * 8];
      if (swap) {
#pragma unroll
        for (int mi = 0; mi < 2; ++mi)
#pragma unroll
          for (int nj = 0; nj < 4; ++nj)
            acc[mi][nj] = __builtin_amdgcn_mfma_f32_16x16x32_bf16(
                bfr[nj], af[mi], acc[mi][nj], 0, 0, 0);
      } else {
#pragma unroll
        for (int mi = 0; mi < 2; ++mi)
#pragma unroll
          for (int nj = 0; nj < 4; ++nj)
            acc[mi][nj] = __builtin_amdgcn_mfma_f32_16x16x32_bf16(
                af[mi], bfr[nj], acc[mi][nj], 0, 0, 0);
      }
    }
    if (ktile < 7) STORELDS(cur ^ 1);
    __syncthreads();
  }
  if (swap) {
    // D^T: row = n (4g+r within nj tile), col = o (c within mi tile)
    int obase = m0 + wr * 32;
    int sec = obase >> 9;  // 0=q, 1=k
    int osec = obase & 511;
    int head = osec >> 6;
    int dbase = osec & 63;
    __bf16* dst = (sec == 0 ? qt : kt) + (size_t)(b * NHEADS + head) * NN * HDIM;
    float scl = (sec == 0) ? QSCALE : 1.0f;
#pragma unroll
    for (int mi = 0; mi < 2; ++mi) {
      float bo = bias[obase + mi * 16 + c];
      int d = dbase + mi * 16 + c;
#pragma unroll
      for (int nj = 0; nj < 4; ++nj)
#pragma unroll
        for (int r = 0; r < 4; ++r) {
          int n = n0 + wc * 64 + nj * 16 + 4 * g + r;
          dst[(size_t)n * HDIM + d] = (__bf16)((acc[mi][nj][r] + bo) * scl);
        }
    }
  } else {
#pragma unroll
    for (int mi = 0; mi < 2; ++mi)
#pragma unroll
      for (int r = 0; r < 4; ++r) {
        int o = m0 + wr * 32 + mi * 16 + 4 * g + r;
        int ch = o - 1024;
        float bo = bias[o];
#pragma unroll
        for (int nj = 0; nj < 4; ++nj) {
          int n = n0 + wc * 64 + nj * 16 + c;
          vbf[((size_t)b * CC + ch) * NN + n] = (__bf16)(acc[mi][nj][r] + bo);
        }
      }
  }
}

// ---------------------------------------------------------------------------
// Kernel 3: flash attention. Both QK^T and PV swapped -> everything (m, l, O)
// is lane-local to q-row c. Defer-rescale (THR=8 in exp2 domain). l is a
// per-lane partial, cross-lane summed once in the epilogue.
// ---------------------------------------------------------------------------
__global__ __launch_bounds__(256, 2) void attn_mfma_kernel(
    const __bf16* __restrict__ qt, const __bf16* __restrict__ ktg,
    const __bf16* __restrict__ vbf, __bf16* __restrict__ xa_t) {
  __shared__ __align__(16) __bf16 Kb[2][64][72];  // 18 KiB
  __shared__ __align__(16) __bf16 Vb[2][64][72];  // 18 KiB
  __shared__ __align__(16) __bf16 Ps[64][72];     // 9 KiB
  int tid = threadIdx.x;
  int wid = tid >> 6, lane = tid & 63;
  int g = lane >> 4, c = lane & 15;
  int n0 = blockIdx.x * 64;
  int h = blockIdx.y, b = blockIdx.z;
  int bh = b * NHEADS + h;
  const __bf16* qbase = qt + ((size_t)bh * NN + n0) * HDIM;
  const __bf16* kbase = ktg + (size_t)bh * NN * HDIM;
  const __bf16* vbase = vbf + ((size_t)b * CC + h * HDIM) * NN;

  int sr = tid >> 2, sc = (tid & 3) * 16;
  bf16x8 kr0 = *(const bf16x8*)(kbase + (size_t)sr * HDIM + sc);
  bf16x8 kr1 = *(const bf16x8*)(kbase + (size_t)sr * HDIM + sc + 8);
  bf16x8 vr0 = *(const bf16x8*)(vbase + (size_t)sr * NN + sc);
  bf16x8 vr1 = *(const bf16x8*)(vbase + (size_t)sr * NN + sc + 8);
  bf16x8 aq0 = *(const bf16x8*)(qbase + (size_t)(wid * 16 + c) * HDIM + g * 8);
  bf16x8 aq1 = *(const bf16x8*)(qbase + (size_t)(wid * 16 + c) * HDIM + 32 + g * 8);
  *(bf16x8*)&Kb[0][sr][sc] = kr0;
  *(bf16x8*)&Kb[0][sr][sc + 8] = kr1;
  *(bf16x8*)&Vb[0][sr][sc] = vr0;
  *(bf16x8*)&Vb[0][sr][sc + 8] = vr1;

  f32x4 O[4] = {};   // O^T: O[dt][r] = O^T[d = dt*16+4g+r][q = c]
  float m_ = -1e30f; // running max for q-row c (uniform across the 4 g-lanes)
  float l_ = 0.f;    // PARTIAL sum (this lane's k-share) for q-row c
  __syncthreads();

  for (int t = 0; t < NN / 64; ++t) {
    int cur = t & 1;
    bool pf = (t + 1 < NN / 64);
    int mt = (t + 1) * 64;
    if (pf) {
      kr0 = *(const bf16x8*)(kbase + (size_t)(mt + sr) * HDIM + sc);
      kr1 = *(const bf16x8*)(kbase + (size_t)(mt + sr) * HDIM + sc + 8);
      vr0 = *(const bf16x8*)(vbase + (size_t)sr * NN + mt + sc);
      vr1 = *(const bf16x8*)(vbase + (size_t)sr * NN + mt + sc + 8);
    }
    // ---- QK^T swapped: st[t4][r] = S[q=c][k=16*t4+4*g+r] ----
    f32x4 st[4];
    __builtin_amdgcn_s_setprio(1);
#pragma unroll
    for (int t4 = 0; t4 < 4; ++t4) {
      bf16x8 bk0 = *(const bf16x8*)&Kb[cur][t4 * 16 + c][g * 8];
      bf16x8 bk1 = *(const bf16x8*)&Kb[cur][t4 * 16 + c][32 + g * 8];
      f32x4 acc = {0.f, 0.f, 0.f, 0.f};
      acc = __builtin_amdgcn_mfma_f32_16x16x32_bf16(bk0, aq0, acc, 0, 0, 0);
      acc = __builtin_amdgcn_mfma_f32_16x16x32_bf16(bk1, aq1, acc, 0, 0, 0);
      st[t4] = acc;
    }
    __builtin_amdgcn_s_setprio(0);
    // ---- tile max (row c lane-local; 2 shuffles over the quad) ----
    float pm = st[0][0];
#pragma unroll
    for (int t4 = 0; t4 < 4; ++t4)
#pragma unroll
      for (int r = 0; r < 4; ++r) pm = fmaxf(pm, st[t4][r]);
    pm = fmaxf(pm, __shfl_xor(pm, 16));
    pm = fmaxf(pm, __shfl_xor(pm, 32));
    // ---- defer-rescale: only touch m/O/l when max grew by > 8 (2^8 bound)
    if (!__all(pm <= m_ + 8.0f)) {
      float mn = fmaxf(m_, pm);
      float fs = exp2f(m_ - mn);
      m_ = mn;
      l_ *= fs;
#pragma unroll
      for (int dt = 0; dt < 4; ++dt)
#pragma unroll
        for (int r = 0; r < 4; ++r) O[dt][r] *= fs;
    }
    float ps = 0.f;
#pragma unroll
    for (int t4 = 0; t4 < 4; ++t4) {
      float p0 = exp2f(st[t4][0] - m_);
      float p1 = exp2f(st[t4][1] - m_);
      float p2 = exp2f(st[t4][2] - m_);
      float p3 = exp2f(st[t4][3] - m_);
      ps += (p0 + p1) + (p2 + p3);
      bf16x4 quad = {(__bf16)p0, (__bf16)p1, (__bf16)p2, (__bf16)p3};
      *(bf16x4*)&Ps[wid * 16 + c][t4 * 16 + 4 * g] = quad;
    }
    l_ += ps;
    // ---- PV swapped: O^T += V^T P^T ----
    bf16x8 ap0 = *(const bf16x8*)&Ps[wid * 16 + c][g * 8];
    bf16x8 ap1 = *(const bf16x8*)&Ps[wid * 16 + c][32 + g * 8];
    __builtin_amdgcn_s_setprio(1);
#pragma unroll
    for (int dt = 0; dt < 4; ++dt) {
      bf16x8 bv0 = *(const bf16x8*)&Vb[cur][dt * 16 + c][g * 8];
      bf16x8 bv1 = *(const bf16x8*)&Vb[cur][dt * 16 + c][32 + g * 8];
      O[dt] = __builtin_amdgcn_mfma_f32_16x16x32_bf16(bv0, ap0, O[dt], 0, 0, 0);
      O[dt] = __builtin_amdgcn_mfma_f32_16x16x32_bf16(bv1, ap1, O[dt], 0, 0, 0);
    }
    __builtin_amdgcn_s_setprio(0);
    if (pf) {
      *(bf16x8*)&Kb[cur ^ 1][sr][sc] = kr0;
      *(bf16x8*)&Kb[cur ^ 1][sr][sc + 8] = kr1;
      *(bf16x8*)&Vb[cur ^ 1][sr][sc] = vr0;
      *(bf16x8*)&Vb[cur ^ 1][sr][sc + 8] = vr1;
    }
    __syncthreads();
  }
  // epilogue: one cross-lane sum for l, then packed 8B stores of O^T rows
  float lt = l_ + __shfl_xor(l_, 16);
  lt += __shfl_xor(lt, 32);
  float inv = 1.0f / lt;
  size_t row = (size_t)b * NN + n0 + wid * 16 + c;
#pragma unroll
  for (int dt = 0; dt < 4; ++dt) {
    bf16x4 pk = {(__bf16)(O[dt][0] * inv), (__bf16)(O[dt][1] * inv),
                 (__bf16)(O[dt][2] * inv), (__bf16)(O[dt][3] * inv)};
    *(bf16x4*)&xa_t[row * CC + h * HDIM + dt * 16 + 4 * g] = pk;
  }
}

// ---------------------------------------------------------------------------
// Kernel 4: proj GEMM, reg-staged double-buffered LDS, 1 barrier per K-step,
// bias + residual(normalized x, fp32) epilogue.
// ---------------------------------------------------------------------------
__global__ __launch_bounds__(256) void proj_mfma_kernel(
    const __bf16* __restrict__ xa_t, const float* __restrict__ w,
    const float* __restrict__ bias, const float* __restrict__ x,
    const float* __restrict__ mu, const float* __restrict__ rstd,
    const float* __restrict__ lnw, const float* __restrict__ lnb,
    float* __restrict__ out) {
  __shared__ __align__(16) __bf16 As[2][64][68];
  __shared__ __align__(16) __bf16 Bs[2][64][68];
  int n0 = blockIdx.x * 64;
  int m0 = blockIdx.y * 64;
  int b = blockIdx.z;
  int tid = threadIdx.x;
  int wid = tid >> 6, lane = tid & 63;
  int g = lane >> 4, c = lane & 15;
  int wr = wid >> 1, wc = wid & 1;
  const __bf16* xab = xa_t + (size_t)b * NN * CC;
  int arow = tid >> 4, ac4 = tid & 15;
  int brow = tid >> 3, bc8 = tid & 7;

  float4 wA[4];
  bf16x8 xB[2];
  auto LOADREGS = [&](int k0) {
#pragma unroll
    for (int l = 0; l < 4; ++l)
      wA[l] = *(const float4*)&w[(size_t)(m0 + arow + 16 * l) * CC + k0 + ac4 * 4];
#pragma unroll
    for (int l = 0; l < 2; ++l)
      xB[l] = *(const bf16x8*)&xab[(size_t)(n0 + brow + 32 * l) * CC + k0 + bc8 * 8];
  };
  auto STORELDS = [&](int buf) {
#pragma unroll
    for (int l = 0; l < 4; ++l) {
      bf16x4 pk = {(__bf16)wA[l].x, (__bf16)wA[l].y, (__bf16)wA[l].z,
                   (__bf16)wA[l].w};
      *(bf16x4*)&As[buf][arow + 16 * l][ac4 * 4] = pk;
    }
#pragma unroll
    for (int l = 0; l < 2; ++l)
      *(bf16x8*)&Bs[buf][brow + 32 * l][bc8 * 8] = xB[l];
  };

  LOADREGS(0);
  STORELDS(0);
  __syncthreads();
  f32x4 acc[2][2] = {};
  for (int ktile = 0; ktile < 8; ++ktile) {
    int cur = ktile & 1;
    if (ktile < 7) LOADREGS((ktile + 1) * 64);
#pragma unroll
    for (int hh = 0; hh < 2; ++hh) {
      bf16x8 af[2], bfr[2];
#pragma unroll
      for (int mi = 0; mi < 2; ++mi)
        af[mi] = *(const bf16x8*)&As[cur][wr * 32 + mi * 16 + c][hh * 32 + g * 8];
#pragma unroll
      for (int nj = 0; nj < 2; ++nj)
        bfr[nj] = *(const bf16x8*)&Bs[cur][wc * 32 + nj * 16 + c][hh * 32 + g * 8];
#pragma unroll
      for (int mi = 0; mi < 2; ++mi)
#pragma unroll
        for (int nj = 0; nj < 2; ++nj)
          acc[mi][nj] = __builtin_amdgcn_mfma_f32_16x16x32_bf16(
              af[mi], bfr[nj], acc[mi][nj], 0, 0, 0);
    }
    if (ktile < 7) STORELDS(cur ^ 1);
    __syncthreads();
  }
#pragma unroll
  for (int mi = 0; mi < 2; ++mi)
#pragma unroll
    for (int r = 0; r < 4; ++r) {
      int o = m0 + wr * 32 + mi * 16 + 4 * g + r;
      float bo = bias[o], gw = lnw[o], gb = lnb[o];
#pragma unroll
      for (int nj = 0; nj < 2; ++nj) {
        int n = n0 + wc * 32 + nj * 16 + c;
        int tok = b * NN + n;
        float xv = x[((size_t)b * CC + o) * NN + n];
        float xlnv = (xv - mu[tok]) * rstd[tok] * gw + gb;
        out[((size_t)b * CC + o) * NN + n] = acc[mi][nj][r] + bo + xlnv;
      }
    }
}

// ---------------------------------------------------------------------------
extern "C" void kernel_launch(void* const* d_in, const int* in_sizes, int n_in,
                              void* d_out, int out_size, void* d_ws, size_t ws_size,
                              hipStream_t stream) {
  const float* x = (const float*)d_in[0];
  const float* lnw = (const float*)d_in[1];
  const float* lnb = (const float*)d_in[2];
  const float* wqkv = (const float*)d_in[3];
  const float* bqkv = (const float*)d_in[4];
  const float* wproj = (const float*)d_in[5];
  const float* bproj = (const float*)d_in[6];
  float* out = (float*)d_out;
  (void)in_sizes; (void)n_in; (void)out_size; (void)ws_size;

  char* wsb = (char*)d_ws;
  float* mu = (float*)wsb;                               // 16 KB
  float* rstd = mu + 4096;                               // 16 KB
  const size_t HSZ = (size_t)BB * NHEADS * NN * HDIM;    // 2M elems
  __bf16* qt = (__bf16*)(wsb + 32768);                   // 4 MB
  __bf16* kt = qt + HSZ;                                 // 4 MB
  __bf16* vbf = kt + HSZ;                                // 4 MB
  __bf16* xln_t = vbf + HSZ;                             // 4 MB
  __bf16* xa_t = xln_t + HSZ;                            // 4 MB

  hipLaunchKernelGGL(ln_stats_kernel, dim3(256), dim3(256), 0, stream, x, mu, rstd);
  hipLaunchKernelGGL(ln_transpose_kernel, dim3(32, 8, 2), dim3(256), 0, stream,
                     x, mu, rstd, lnw, lnb, xln_t);
  hipLaunchKernelGGL(qkv_mfma_kernel, dim3(16, 24, 2), dim3(256), 0, stream,
                     xln_t, wqkv, bqkv, qt, kt, vbf);
  hipLaunchKernelGGL(attn_mfma_kernel, dim3(32, 8, 2), dim3(256), 0, stream,
                     qt, kt, vbf, xa_t);
  hipLaunchKernelGGL(proj_mfma_kernel, dim3(32, 8, 2), dim3(256), 0, stream,
                     xa_t, wproj, bproj, x, mu, rstd, lnw, lnb, out);
}